// Round 1
// baseline (712.299 us; speedup 1.0000x reference)
//
#include <hip/hip_runtime.h>

typedef unsigned short u16;
typedef unsigned int u32;
typedef float f32x4 __attribute__((ext_vector_type(4)));
typedef short s16x8 __attribute__((ext_vector_type(8)));
typedef u16 u16x4 __attribute__((ext_vector_type(4)));
typedef u32 u32x4 __attribute__((ext_vector_type(4)));

#define DEVI static __device__ __forceinline__

DEVI u16 f2bf(float f) {
  u32 u = __float_as_uint(f);
  return (u16)((u + 0x7fffu + ((u >> 16) & 1u)) >> 16);
}

DEVI void g2l16(const void* g, void* l) {
  __builtin_amdgcn_global_load_lds((const __attribute__((address_space(1))) u32*)g,
                                   (__attribute__((address_space(3))) u32*)l,
                                   16, 0, 0);
}

// ---------------------------------------------------------------------------
// Weight transpose/convert: dst[c*R + r] = bf16(src[r*C + c])
// ---------------------------------------------------------------------------
__global__ __launch_bounds__(256) void trans_w(
    const float* __restrict__ src, u16* __restrict__ dst, int R, int C)
{
  __shared__ __attribute__((aligned(16))) u16 tile[64 * 65];
  const int t = threadIdx.x;
  const int c0 = blockIdx.x * 64, r0 = blockIdx.y * 64;
#pragma unroll
  for (int i = 0; i < 16; ++i) {
    const int idx = i * 256 + t;
    const int c = idx & 63, r = idx >> 6;
    tile[c * 65 + r] = f2bf(src[(long)(r0 + r) * C + c0 + c]);
  }
  __syncthreads();
#pragma unroll
  for (int i = 0; i < 16; ++i) {
    const int idx = i * 256 + t;
    const int r = idx & 63, c = idx >> 6;
    dst[(long)(c0 + c) * R + r0 + r] = tile[c * 65 + r];
  }
}

// QKV weights [H,C,HD] (x3) -> concat B^T layout [3*1024 rows n = mat*1024+h*64+d][1024 cols c]
__global__ __launch_bounds__(256) void trans_qkvw(
    const float* __restrict__ Wq, const float* __restrict__ Wk,
    const float* __restrict__ Wv, u16* __restrict__ dst)
{
  __shared__ __attribute__((aligned(16))) u16 tile[64 * 65];
  const int t = threadIdx.x;
  const int c0 = blockIdx.x * 64;
  const int mh = blockIdx.y;
  const int mat = mh >> 4, h = mh & 15;
  const float* src = (mat == 0 ? Wq : (mat == 1 ? Wk : Wv)) + (long)h * 65536;
#pragma unroll
  for (int i = 0; i < 16; ++i) {
    const int idx = i * 256 + t;
    const int d = idx & 63, c = idx >> 6;
    tile[d * 65 + c] = f2bf(src[(long)(c0 + c) * 64 + d]);
  }
  __syncthreads();
  const long nb = (long)(mat * 1024 + h * 64);
#pragma unroll
  for (int i = 0; i < 16; ++i) {
    const int idx = i * 256 + t;
    const int d = idx >> 6, c = idx & 63;
    dst[(nb + d) * 1024 + c0 + c] = tile[d * 65 + c];
  }
}

// ---------------------------------------------------------------------------
// LayerNorm: one wave per 1024-col row, fp32 in -> bf16 out
// ---------------------------------------------------------------------------
__global__ __launch_bounds__(256) void ln_kernel(
    const float* __restrict__ x, const float* __restrict__ g,
    const float* __restrict__ be, u16* __restrict__ out)
{
  const int t = threadIdx.x, wv = t >> 6, l = t & 63;
  const long row = (long)blockIdx.x * 4 + wv;
  const float* xr = x + row * 1024;
  f32x4 v[4];
#pragma unroll
  for (int i = 0; i < 4; ++i) v[i] = *(const f32x4*)(xr + i * 256 + l * 4);
  float s = 0.f, sq = 0.f;
#pragma unroll
  for (int i = 0; i < 4; ++i)
#pragma unroll
    for (int j = 0; j < 4; ++j) { s += v[i][j]; sq += v[i][j] * v[i][j]; }
#pragma unroll
  for (int mask = 1; mask < 64; mask <<= 1) {
    s  += __shfl_xor(s, mask);
    sq += __shfl_xor(sq, mask);
  }
  const float mean = s * (1.f / 1024.f);
  const float var  = sq * (1.f / 1024.f) - mean * mean;
  const float rs = rsqrtf(var + 1e-5f);
#pragma unroll
  for (int i = 0; i < 4; ++i) {
    f32x4 gv = *(const f32x4*)(g  + i * 256 + l * 4);
    f32x4 bv = *(const f32x4*)(be + i * 256 + l * 4);
    u16x4 o;
#pragma unroll
    for (int j = 0; j < 4; ++j) o[j] = f2bf((v[i][j] - mean) * rs * gv[j] + bv[j]);
    *(u16x4*)(out + row * 1024 + i * 256 + l * 4) = o;
  }
}

// ---------------------------------------------------------------------------
// GEMM (m97 structure): C[M,N] = A[M,K] * Bt[N,K]^T, 128x128 tile, BK=32,
// 4 waves each 64x64 (4x4 of 16x16x32 bf16 MFMA), global_load_lds staging.
// ---------------------------------------------------------------------------
template <typename OutT, bool RELU, bool BIAS, bool RESID>
__global__ __launch_bounds__(256) void gemm_bt(
    const u16* __restrict__ A, const u16* __restrict__ Bt,
    OutT* __restrict__ Cout, const float* __restrict__ bias,
    const float* __restrict__ resid, int M, int N, int K)
{
  __shared__ __attribute__((aligned(16))) u16 As[4096];
  __shared__ __attribute__((aligned(16))) u16 Bs[4096];
  const int t  = threadIdx.x;
  const int l  = t & 63;
  const int wv = t >> 6;
  const int lr = l & 15, lg = l >> 4;
  const int wr = wv >> 1, wc = wv & 1;
  const long m0 = (long)blockIdx.x * 128, n0 = (long)blockIdx.y * 128;

  const int srow = t >> 2;
  const int scol = (t & 3) << 3;

  f32x4 acc[4][4] = {};

  const u16* Ap = A  + (m0 + srow) * K + scol;
  const u16* Bp = Bt + (n0 + srow) * K + scol;
  char* Asd = (char*)As + t * 16;
  char* Bsd = (char*)Bs + t * 16;

  for (int k0 = 0; k0 < K; k0 += 32) {
    __syncthreads();
    g2l16(Ap + k0,               Asd);
    g2l16(Ap + (long)64 * K + k0, Asd + 4096);
    g2l16(Bp + k0,               Bsd);
    g2l16(Bp + (long)64 * K + k0, Bsd + 4096);
    __syncthreads();
    s16x8 af[4], bfr[4];
#pragma unroll
    for (int m = 0; m < 4; ++m)
      af[m] = *(const s16x8*)(As + (wr * 64 + m * 16 + lr) * 32 + lg * 8);
#pragma unroll
    for (int n = 0; n < 4; ++n)
      bfr[n] = *(const s16x8*)(Bs + (wc * 64 + n * 16 + lr) * 32 + lg * 8);
#pragma unroll
    for (int m = 0; m < 4; ++m)
#pragma unroll
      for (int n = 0; n < 4; ++n)
        acc[m][n] = __builtin_amdgcn_mfma_f32_16x16x32_bf16(af[m], bfr[n], acc[m][n], 0, 0, 0);
  }

  float bv[4];
#pragma unroll
  for (int n = 0; n < 4; ++n)
    bv[n] = BIAS ? bias[n0 + wc * 64 + n * 16 + lr] : 0.f;

#pragma unroll
  for (int m = 0; m < 4; ++m) {
#pragma unroll
    for (int i = 0; i < 4; ++i) {
      const long row = m0 + wr * 64 + m * 16 + lg * 4 + i;
#pragma unroll
      for (int n = 0; n < 4; ++n) {
        const long col = n0 + wc * 64 + n * 16 + lr;
        float v = acc[m][n][i] + bv[n];
        if (RESID) v += resid[row * N + col];
        if (RELU)  v = fmaxf(v, 0.f);
        if constexpr (sizeof(OutT) == 2) Cout[row * N + col] = f2bf(v);
        else                             Cout[row * N + col] = v;
      }
    }
  }
}

// ---------------------------------------------------------------------------
// Flash attention, causal, 16 heads, HD=64. qkv: [B*T, 3072] bf16
// block = 4 waves; wave handles 16 q rows; chunks of 32 kv rows.
// out: [B*T, 1024] bf16 (head-concat layout)
// ---------------------------------------------------------------------------
__global__ __launch_bounds__(256) void attn_kernel(
    const u16* __restrict__ qkv, u16* __restrict__ out)
{
  __shared__ __attribute__((aligned(16))) u16 Klds[2048];    // [32][64], 16B-chunk XOR swizzle
  __shared__ __attribute__((aligned(16))) u16 Vlds[32 * 66]; // [32][64] pad stride 66
  __shared__ __attribute__((aligned(16))) u16 Plds[4][512];  // per-wave [16][32], chunk-XOR

  const int t  = threadIdx.x;
  const int wv = t >> 6, l = t & 63;
  const int lr = l & 15, lg = l >> 4;
  const int qt = blockIdx.x;
  const int bh = blockIdx.y;
  const long bt0 = (long)(bh >> 4) * 2048;
  const int h = bh & 15;
  const int qrow = qt * 64 + wv * 16;

  const u16* qp = qkv + (bt0 + qrow + lr) * 3072 + h * 64 + lg * 8;
  const s16x8 aq0 = *(const s16x8*)qp;
  const s16x8 aq1 = *(const s16x8*)(qp + 32);

  f32x4 O[4] = {};
  float mi[4], li[4];
#pragma unroll
  for (int i = 0; i < 4; ++i) { mi[i] = -__builtin_inff(); li[i] = 0.f; }

  const int srow = t >> 3;                        // 0..31
  const int kcol = ((t & 7) ^ (srow & 7)) << 3;   // pre-swizzled source col for K
  const int vcol = (t & 7) << 3;
  const u16* kb = qkv + (bt0 + srow) * 3072 + 1024 + h * 64 + kcol;
  const u16* vb = qkv + (bt0 + srow) * 3072 + 2048 + h * 64 + vcol;
  u32* vd = (u32*)(Vlds + srow * 66 + vcol);

  const int nch = qt * 2 + 2;
  for (int scn = 0; scn < nch; ++scn) {
    const long soff = (long)scn * 32 * 3072;
    __syncthreads();
    g2l16(kb + soff, (char*)Klds + t * 16);
    u32x4 vvv = *(const u32x4*)(vb + soff);
    vd[0] = vvv[0]; vd[1] = vvv[1]; vd[2] = vvv[2]; vd[3] = vvv[3];
    __syncthreads();

    const int s0 = scn * 32;
    f32x4 S[2];
#pragma unroll
    for (int sh = 0; sh < 2; ++sh) {
      const int row = sh * 16 + lr;
      const u32 sw = (u32)((row & 7) << 4);
      const char* kp = (const char*)Klds;
      s16x8 bk0 = *(const s16x8*)(kp + (((u32)(row * 128 + lg * 16)) ^ sw));
      s16x8 bk1 = *(const s16x8*)(kp + (((u32)(row * 128 + 64 + lg * 16)) ^ sw));
      f32x4 z = {};
      z = __builtin_amdgcn_mfma_f32_16x16x32_bf16(aq0, bk0, z, 0, 0, 0);
      z = __builtin_amdgcn_mfma_f32_16x16x32_bf16(aq1, bk1, z, 0, 0, 0);
      S[sh] = z;
    }

    float mt[4];
#pragma unroll
    for (int i = 0; i < 4; ++i) {
      const int qg = qrow + lg * 4 + i;
      float a0 = (s0 + lr      <= qg) ? S[0][i] * 0.125f : -__builtin_inff();
      float a1 = (s0 + 16 + lr <= qg) ? S[1][i] * 0.125f : -__builtin_inff();
      S[0][i] = a0; S[1][i] = a1;
      mt[i] = fmaxf(a0, a1);
    }
#pragma unroll
    for (int mask = 1; mask < 16; mask <<= 1)
#pragma unroll
      for (int i = 0; i < 4; ++i)
        mt[i] = fmaxf(mt[i], __shfl_xor(mt[i], mask));

    float so[4];
#pragma unroll
    for (int i = 0; i < 4; ++i) {
      const float mn = fmaxf(mi[i], mt[i]);
      so[i] = __expf(mi[i] - mn);
      mi[i] = mn;
    }

#pragma unroll
    for (int i = 0; i < 4; ++i) {
      const float p0 = __expf(S[0][i] - mi[i]);
      const float p1 = __expf(S[1][i] - mi[i]);
      li[i] = li[i] * so[i] + p0 + p1;
      const int q_l = lg * 4 + i;
      const int c0 = lr >> 3;
      Plds[wv][q_l * 32 + (((c0    ) ^ lg) & 3) * 8 + (lr & 7)] = f2bf(p0);
      Plds[wv][q_l * 32 + (((c0 + 2) ^ lg) & 3) * 8 + (lr & 7)] = f2bf(p1);
    }
#pragma unroll
    for (int cb = 0; cb < 4; ++cb)
#pragma unroll
      for (int i = 0; i < 4; ++i) O[cb][i] *= so[i];

    const s16x8 pa = *(const s16x8*)(&Plds[wv][lr * 32 + ((lg ^ (lr >> 2)) & 3) * 8]);
#pragma unroll
    for (int cb = 0; cb < 4; ++cb) {
      s16x8 vbf;
#pragma unroll
      for (int j = 0; j < 8; ++j)
        vbf[j] = (short)Vlds[(lg * 8 + j) * 66 + cb * 16 + lr];
      O[cb] = __builtin_amdgcn_mfma_f32_16x16x32_bf16(pa, vbf, O[cb], 0, 0, 0);
    }
  }

#pragma unroll
  for (int mask = 1; mask < 16; mask <<= 1)
#pragma unroll
    for (int i = 0; i < 4; ++i)
      li[i] += __shfl_xor(li[i], mask);

#pragma unroll
  for (int i = 0; i < 4; ++i) {
    const float rl = 1.f / li[i];
    const long obase = (bt0 + qrow + lg * 4 + i) * 1024 + h * 64 + lr;
#pragma unroll
    for (int cb = 0; cb < 4; ++cb)
      out[obase + cb * 16] = f2bf(O[cb][i] * rl);
  }
}

// ---------------------------------------------------------------------------
extern "C" void kernel_launch(void* const* d_in, const int* in_sizes, int n_in,
                              void* d_out, int out_size, void* d_ws, size_t ws_size,
                              hipStream_t stream)
{
  const float* x   = (const float*)d_in[0];
  const float* Wq  = (const float*)d_in[1];
  const float* Wk  = (const float*)d_in[2];
  const float* Wv  = (const float*)d_in[3];
  const float* Wo  = (const float*)d_in[4];
  const float* bo  = (const float*)d_in[5];
  const float* W1  = (const float*)d_in[6];
  const float* b1  = (const float*)d_in[7];
  const float* W2  = (const float*)d_in[8];
  const float* b2  = (const float*)d_in[9];
  const float* g1  = (const float*)d_in[10];
  const float* be1 = (const float*)d_in[11];
  const float* g2  = (const float*)d_in[12];
  const float* be2 = (const float*)d_in[13];
  float* outp = (float*)d_out;

  char* ws = (char*)d_ws;
  u16*   qkvT = (u16*)ws;                       //  6,291,456  B  [3072,1024] bf16
  u16*   woT  = (u16*)(ws + 6291456);           //  2,097,152
  u16*   w1T  = (u16*)(ws + 8388608);           //  8,388,608  [4096,1024]
  u16*   w2T  = (u16*)(ws + 16777216);          //  8,388,608  [1024,4096]
  float* x2   = (float*)(ws + 25165824);        // 33,554,432  [8192,1024] f32
  u16*   attno= (u16*)(ws + 58720256);          // 16,777,216
  u16*   h2   = (u16*)(ws + 75497472);          // 16,777,216
  u16*   hbf  = (u16*)(ws + 92274688);          // 16,777,216
  u16*   qkvb = (u16*)(ws + 109051904);         // 50,331,648  [8192,3072]
  u16*   ffn1 = (u16*)(ws + 92274688);          // reuse hbf+qkvb region: 67,108,864
  (void)in_sizes; (void)n_in; (void)out_size; (void)ws_size;

  // weight conversion (every call; ws is re-poisoned by the harness)
  trans_qkvw<<<dim3(16, 48), 256, 0, stream>>>(Wq, Wk, Wv, qkvT);
  trans_w<<<dim3(16, 16), 256, 0, stream>>>(Wo, woT, 1024, 1024);
  trans_w<<<dim3(64, 16), 256, 0, stream>>>(W1, w1T, 1024, 4096);
  trans_w<<<dim3(16, 64), 256, 0, stream>>>(W2, w2T, 4096, 1024);

  // LN1 -> h (bf16)
  ln_kernel<<<2048, 256, 0, stream>>>(x, g1, be1, hbf);
  // QKV projection: [8192,1024] x [1024,3072] -> bf16
  gemm_bt<u16, false, false, false><<<dim3(64, 24), 256, 0, stream>>>(
      hbf, qkvT, qkvb, nullptr, nullptr, 8192, 3072, 1024);
  // causal flash attention
  attn_kernel<<<dim3(32, 64), 256, 0, stream>>>(qkvb, attno);
  // output projection + bias + residual -> x2 (f32)
  gemm_bt<float, false, true, true><<<dim3(64, 8), 256, 0, stream>>>(
      attno, woT, x2, bo, x, 8192, 1024, 1024);
  // LN2 -> h2 (bf16)
  ln_kernel<<<2048, 256, 0, stream>>>(x2, g2, be2, h2);
  // FFN1 + bias + relu -> bf16
  gemm_bt<u16, true, true, false><<<dim3(64, 32), 256, 0, stream>>>(
      h2, w1T, ffn1, b1, nullptr, 8192, 4096, 1024);
  // FFN2 + bias + residual -> d_out (f32)
  gemm_bt<float, false, true, true><<<dim3(64, 8), 256, 0, stream>>>(
      ffn1, w2T, outp, b2, x2, 8192, 1024, 4096);
}

// Round 2
// 666.670 us; speedup vs baseline: 1.0684x; 1.0684x over previous
//
#include <hip/hip_runtime.h>

typedef unsigned short u16;
typedef unsigned int u32;
typedef float f32x4 __attribute__((ext_vector_type(4)));
typedef short s16x8 __attribute__((ext_vector_type(8)));
typedef u16 u16x4 __attribute__((ext_vector_type(4)));
typedef u32 u32x4 __attribute__((ext_vector_type(4)));

#define DEVI static __device__ __forceinline__

DEVI u16 f2bf(float f) {
  u32 u = __float_as_uint(f);
  return (u16)((u + 0x7fffu + ((u >> 16) & 1u)) >> 16);
}

DEVI void g2l16(const void* g, void* l) {
  __builtin_amdgcn_global_load_lds((const __attribute__((address_space(1))) u32*)g,
                                   (__attribute__((address_space(3))) u32*)l,
                                   16, 0, 0);
}

// ---------------------------------------------------------------------------
// Weight transpose/convert: dst[c*R + r] = bf16(src[r*C + c])
// ---------------------------------------------------------------------------
__global__ __launch_bounds__(256) void trans_w(
    const float* __restrict__ src, u16* __restrict__ dst, int R, int C)
{
  __shared__ __attribute__((aligned(16))) u16 tile[64 * 65];
  const int t = threadIdx.x;
  const int c0 = blockIdx.x * 64, r0 = blockIdx.y * 64;
#pragma unroll
  for (int i = 0; i < 16; ++i) {
    const int idx = i * 256 + t;
    const int c = idx & 63, r = idx >> 6;
    tile[c * 65 + r] = f2bf(src[(long)(r0 + r) * C + c0 + c]);
  }
  __syncthreads();
#pragma unroll
  for (int i = 0; i < 16; ++i) {
    const int idx = i * 256 + t;
    const int r = idx & 63, c = idx >> 6;
    dst[(long)(c0 + c) * R + r0 + r] = tile[c * 65 + r];
  }
}

// QKV weights [H,C,HD] (x3) -> concat B^T layout [3*1024 rows][1024 cols]
__global__ __launch_bounds__(256) void trans_qkvw(
    const float* __restrict__ Wq, const float* __restrict__ Wk,
    const float* __restrict__ Wv, u16* __restrict__ dst)
{
  __shared__ __attribute__((aligned(16))) u16 tile[64 * 65];
  const int t = threadIdx.x;
  const int c0 = blockIdx.x * 64;
  const int mh = blockIdx.y;
  const int mat = mh >> 4, h = mh & 15;
  const float* src = (mat == 0 ? Wq : (mat == 1 ? Wk : Wv)) + (long)h * 65536;
#pragma unroll
  for (int i = 0; i < 16; ++i) {
    const int idx = i * 256 + t;
    const int d = idx & 63, c = idx >> 6;
    tile[d * 65 + c] = f2bf(src[(long)(c0 + c) * 64 + d]);
  }
  __syncthreads();
  const long nb = (long)(mat * 1024 + h * 64);
#pragma unroll
  for (int i = 0; i < 16; ++i) {
    const int idx = i * 256 + t;
    const int d = idx >> 6, c = idx & 63;
    dst[(nb + d) * 1024 + c0 + c] = tile[d * 65 + c];
  }
}

// ---------------------------------------------------------------------------
// V transpose: qkv[B*T,3072] V-part -> Vt[bh][64 d][2048 t] bf16
// u32-packed LDS tile (r-pairs) for conflict-free transpose.
// ---------------------------------------------------------------------------
__global__ __launch_bounds__(256) void vtrans(
    const u16* __restrict__ qkv, u16* __restrict__ vtg)
{
  __shared__ __attribute__((aligned(16))) u32 tile[64 * 33];
  const int t = threadIdx.x;
  const int tt = blockIdx.x, bh = blockIdx.y;
  const long bt0 = (long)(bh >> 4) * 2048;
  const int h = bh & 15;
  const int t0 = tt * 64;
  const int r2 = t >> 3, c8 = t & 7;
  const u16* src = qkv + (bt0 + t0 + 2 * r2) * 3072 + 2048 + h * 64 + c8 * 8;
  const s16x8 a = *(const s16x8*)src;
  const s16x8 b = *(const s16x8*)(src + 3072);
#pragma unroll
  for (int j = 0; j < 8; ++j)
    tile[(c8 * 8 + j) * 33 + r2] = (u32)(u16)a[j] | ((u32)(u16)b[j] << 16);
  __syncthreads();
#pragma unroll
  for (int it = 0; it < 2; ++it) {
    const int idx = it * 256 + t;
    const int d = idx >> 3, tc = idx & 7;
    u32x4 w;
#pragma unroll
    for (int q = 0; q < 4; ++q) w[q] = tile[d * 33 + tc * 4 + q];
    *(u32x4*)(vtg + (long)bh * 131072 + (long)d * 2048 + t0 + tc * 8) = w;
  }
}

// ---------------------------------------------------------------------------
// LayerNorm: one wave per 1024-col row, fp32 in -> bf16 out
// ---------------------------------------------------------------------------
__global__ __launch_bounds__(256) void ln_kernel(
    const float* __restrict__ x, const float* __restrict__ g,
    const float* __restrict__ be, u16* __restrict__ out)
{
  const int t = threadIdx.x, wv = t >> 6, l = t & 63;
  const long row = (long)blockIdx.x * 4 + wv;
  const float* xr = x + row * 1024;
  f32x4 v[4];
#pragma unroll
  for (int i = 0; i < 4; ++i) v[i] = *(const f32x4*)(xr + i * 256 + l * 4);
  float s = 0.f, sq = 0.f;
#pragma unroll
  for (int i = 0; i < 4; ++i)
#pragma unroll
    for (int j = 0; j < 4; ++j) { s += v[i][j]; sq += v[i][j] * v[i][j]; }
#pragma unroll
  for (int mask = 1; mask < 64; mask <<= 1) {
    s  += __shfl_xor(s, mask);
    sq += __shfl_xor(sq, mask);
  }
  const float mean = s * (1.f / 1024.f);
  const float var  = sq * (1.f / 1024.f) - mean * mean;
  const float rs = rsqrtf(var + 1e-5f);
#pragma unroll
  for (int i = 0; i < 4; ++i) {
    f32x4 gv = *(const f32x4*)(g  + i * 256 + l * 4);
    f32x4 bv = *(const f32x4*)(be + i * 256 + l * 4);
    u16x4 o;
#pragma unroll
    for (int j = 0; j < 4; ++j) o[j] = f2bf((v[i][j] - mean) * rs * gv[j] + bv[j]);
    *(u16x4*)(out + row * 1024 + i * 256 + l * 4) = o;
  }
}

// ---------------------------------------------------------------------------
// GEMM (m97 structure): C[M,N] = A[M,K] * Bt[N,K]^T, 128x128 tile, BK=32
// ---------------------------------------------------------------------------
template <typename OutT, bool RELU, bool BIAS, bool RESID>
__global__ __launch_bounds__(256) void gemm_bt(
    const u16* __restrict__ A, const u16* __restrict__ Bt,
    OutT* __restrict__ Cout, const float* __restrict__ bias,
    const float* __restrict__ resid, int M, int N, int K)
{
  __shared__ __attribute__((aligned(16))) u16 As[4096];
  __shared__ __attribute__((aligned(16))) u16 Bs[4096];
  const int t  = threadIdx.x;
  const int l  = t & 63;
  const int wv = t >> 6;
  const int lr = l & 15, lg = l >> 4;
  const int wr = wv >> 1, wc = wv & 1;
  const long m0 = (long)blockIdx.x * 128, n0 = (long)blockIdx.y * 128;

  const int srow = t >> 2;
  const int scol = (t & 3) << 3;

  f32x4 acc[4][4] = {};

  const u16* Ap = A  + (m0 + srow) * K + scol;
  const u16* Bp = Bt + (n0 + srow) * K + scol;
  char* Asd = (char*)As + t * 16;
  char* Bsd = (char*)Bs + t * 16;

  for (int k0 = 0; k0 < K; k0 += 32) {
    __syncthreads();
    g2l16(Ap + k0,                Asd);
    g2l16(Ap + (long)64 * K + k0, Asd + 4096);
    g2l16(Bp + k0,                Bsd);
    g2l16(Bp + (long)64 * K + k0, Bsd + 4096);
    __syncthreads();
    s16x8 af[4], bfr[4];
#pragma unroll
    for (int m = 0; m < 4; ++m)
      af[m] = *(const s16x8*)(As + (wr * 64 + m * 16 + lr) * 32 + lg * 8);
#pragma unroll
    for (int n = 0; n < 4; ++n)
      bfr[n] = *(const s16x8*)(Bs + (wc * 64 + n * 16 + lr) * 32 + lg * 8);
#pragma unroll
    for (int m = 0; m < 4; ++m)
#pragma unroll
      for (int n = 0; n < 4; ++n)
        acc[m][n] = __builtin_amdgcn_mfma_f32_16x16x32_bf16(af[m], bfr[n], acc[m][n], 0, 0, 0);
  }

  float bv[4];
#pragma unroll
  for (int n = 0; n < 4; ++n)
    bv[n] = BIAS ? bias[n0 + wc * 64 + n * 16 + lr] : 0.f;

#pragma unroll
  for (int m = 0; m < 4; ++m) {
#pragma unroll
    for (int i = 0; i < 4; ++i) {
      const long row = m0 + wr * 64 + m * 16 + lg * 4 + i;
#pragma unroll
      for (int n = 0; n < 4; ++n) {
        const long col = n0 + wc * 64 + n * 16 + lr;
        float v = acc[m][n][i] + bv[n];
        if (RESID) v += resid[row * N + col];
        if (RELU)  v = fmaxf(v, 0.f);
        if constexpr (sizeof(OutT) == 2) Cout[row * N + col] = f2bf(v);
        else                             Cout[row * N + col] = v;
      }
    }
  }
}

// ---------------------------------------------------------------------------
// Flash attention v2, causal, 16 heads, HD=64.
// Block: 4 waves x 32 q-rows = 128 q rows. KV chunk = 64.
// K from qkv (row-major [kv][64]); V from pre-transposed vtg ([d][t]).
// All LDS tiles 128B rows with (row&7)<<4 XOR swizzle; all frag reads b128.
// ---------------------------------------------------------------------------
__global__ __launch_bounds__(256) void attn_kernel(
    const u16* __restrict__ qkv, const u16* __restrict__ vtg,
    u16* __restrict__ out)
{
  __shared__ __attribute__((aligned(16))) u16 Kl[4096];   // [64 kv][64 d] swz
  __shared__ __attribute__((aligned(16))) u16 Vl[4096];   // [64 d][64 t] swz
  __shared__ __attribute__((aligned(16))) u16 Pl[8192];   // 4 waves x [32 q][64 kv] swz

  const int t  = threadIdx.x;
  const int wv = t >> 6, l = t & 63;
  const int lr = l & 15, lg = l >> 4;
  const int qte = (int)gridDim.x - 1 - (int)blockIdx.x;  // big blocks first
  const int bh = blockIdx.y;
  const long bt0 = (long)(bh >> 4) * 2048;
  const int h = bh & 15;
  const int qrow0 = qte * 128 + wv * 32;

  // Q fragments (A-operand): [m-tile][d-half]
  s16x8 qf[2][2];
#pragma unroll
  for (int m = 0; m < 2; ++m)
#pragma unroll
    for (int dc = 0; dc < 2; ++dc)
      qf[m][dc] = *(const s16x8*)(qkv + (bt0 + qrow0 + m * 16 + lr) * 3072 +
                                  h * 64 + dc * 32 + lg * 8);

  f32x4 O[2][4] = {};
  float mi[2][4], li[2][4];
#pragma unroll
  for (int m = 0; m < 2; ++m)
#pragma unroll
    for (int i = 0; i < 4; ++i) { mi[m][i] = -__builtin_inff(); li[m][i] = 0.f; }

  const int r0 = t >> 3, c8 = t & 7;
  const int swc = (c8 ^ (r0 & 7)) << 3;                   // pre-swizzled source col
  const u16* ksrc = qkv + (bt0 + r0) * 3072 + 1024 + h * 64 + swc;
  const u16* vsrc = vtg + (long)bh * 131072 + (long)r0 * 2048 + swc;
  char* kd = (char*)Kl + t * 16;
  char* vd = (char*)Vl + t * 16;
  char* pw = (char*)Pl + wv * 4096;

  const int nch = qte * 2 + 2;
  for (int scn = 0; scn < nch; ++scn) {
    const int s0 = scn * 64;
    __syncthreads();
    g2l16(ksrc + (long)s0 * 3072,        kd);
    g2l16(ksrc + (long)(s0 + 32) * 3072, kd + 4096);
    g2l16(vsrc + s0,                     vd);
    g2l16(vsrc + s0 + 65536,             vd + 4096);
    __syncthreads();

    if (s0 <= qrow0 + 31) {
      // K fragments (B-operand): [kv-tile][d-half]
      s16x8 kf[4][2];
#pragma unroll
      for (int n = 0; n < 4; ++n) {
        const int row = n * 16 + lr;
        const int sw = (row & 7) << 4;
#pragma unroll
        for (int dh = 0; dh < 2; ++dh)
          kf[n][dh] = *(const s16x8*)((const char*)Kl + row * 128 +
                                      (((dh * 4 + lg) << 4) ^ sw));
      }
      const bool needmask = (s0 + 63 > qrow0);

#pragma unroll
      for (int m = 0; m < 2; ++m) {
        f32x4 S[4];
#pragma unroll
        for (int n = 0; n < 4; ++n) {
          f32x4 z = {};
          z = __builtin_amdgcn_mfma_f32_16x16x32_bf16(qf[m][0], kf[n][0], z, 0, 0, 0);
          S[n] = __builtin_amdgcn_mfma_f32_16x16x32_bf16(qf[m][1], kf[n][1], z, 0, 0, 0);
        }
        float mt[4];
#pragma unroll
        for (int i = 0; i < 4; ++i) {
          const int qg = qrow0 + m * 16 + lg * 4 + i;
          if (needmask) {
#pragma unroll
            for (int n = 0; n < 4; ++n)
              S[n][i] = (s0 + n * 16 + lr <= qg) ? S[n][i] * 0.125f : -__builtin_inff();
          } else {
#pragma unroll
            for (int n = 0; n < 4; ++n) S[n][i] *= 0.125f;
          }
          mt[i] = fmaxf(fmaxf(S[0][i], S[1][i]), fmaxf(S[2][i], S[3][i]));
        }
#pragma unroll
        for (int msk = 1; msk < 16; msk <<= 1)
#pragma unroll
          for (int i = 0; i < 4; ++i)
            mt[i] = fmaxf(mt[i], __shfl_xor(mt[i], msk));

#pragma unroll
        for (int i = 0; i < 4; ++i) {
          const float mn = fmaxf(mi[m][i], mt[i]);
          const float so = __expf(mi[m][i] - mn);
          mi[m][i] = mn;
          float p[4];
#pragma unroll
          for (int n = 0; n < 4; ++n) p[n] = __expf(S[n][i] - mn);
          li[m][i] = li[m][i] * so + (p[0] + p[1]) + (p[2] + p[3]);
#pragma unroll
          for (int n = 0; n < 4; ++n) O[m][n][i] *= so;
          const int q_l = m * 16 + lg * 4 + i;
          char* prow = pw + q_l * 128 + ((lr & 7) << 1);
          const int swp = q_l & 7;
#pragma unroll
          for (int n = 0; n < 4; ++n)
            *(u16*)(prow + (((n * 2 + (lr >> 3)) ^ swp) << 4)) = f2bf(p[n]);
        }
      }

      // V fragments (B-operand): [d-tile][kv-half]
      s16x8 vf[4][2];
#pragma unroll
      for (int dn = 0; dn < 4; ++dn) {
        const int row = dn * 16 + lr;
        const int sw = (row & 7) << 4;
#pragma unroll
        for (int kk = 0; kk < 2; ++kk)
          vf[dn][kk] = *(const s16x8*)((const char*)Vl + row * 128 +
                                       (((kk * 4 + lg) << 4) ^ sw));
      }
#pragma unroll
      for (int m = 0; m < 2; ++m) {
        const int q_l = m * 16 + lr;
        const int swp = (q_l & 7) << 4;
        s16x8 pa[2];
#pragma unroll
        for (int kk = 0; kk < 2; ++kk)
          pa[kk] = *(const s16x8*)(pw + q_l * 128 + (((kk * 4 + lg) << 4) ^ swp));
#pragma unroll
        for (int dn = 0; dn < 4; ++dn) {
          O[m][dn] = __builtin_amdgcn_mfma_f32_16x16x32_bf16(pa[0], vf[dn][0], O[m][dn], 0, 0, 0);
          O[m][dn] = __builtin_amdgcn_mfma_f32_16x16x32_bf16(pa[1], vf[dn][1], O[m][dn], 0, 0, 0);
        }
      }
    }
  }

#pragma unroll
  for (int msk = 1; msk < 16; msk <<= 1)
#pragma unroll
    for (int m = 0; m < 2; ++m)
#pragma unroll
      for (int i = 0; i < 4; ++i)
        li[m][i] += __shfl_xor(li[m][i], msk);

#pragma unroll
  for (int m = 0; m < 2; ++m)
#pragma unroll
    for (int i = 0; i < 4; ++i) {
      const float rl = 1.f / li[m][i];
      const long ob = (bt0 + qrow0 + m * 16 + lg * 4 + i) * 1024 + h * 64 + lr;
#pragma unroll
      for (int n = 0; n < 4; ++n)
        out[ob + n * 16] = f2bf(O[m][n][i] * rl);
    }
}

// ---------------------------------------------------------------------------
extern "C" void kernel_launch(void* const* d_in, const int* in_sizes, int n_in,
                              void* d_out, int out_size, void* d_ws, size_t ws_size,
                              hipStream_t stream)
{
  const float* x   = (const float*)d_in[0];
  const float* Wq  = (const float*)d_in[1];
  const float* Wk  = (const float*)d_in[2];
  const float* Wv  = (const float*)d_in[3];
  const float* Wo  = (const float*)d_in[4];
  const float* bo  = (const float*)d_in[5];
  const float* W1  = (const float*)d_in[6];
  const float* b1  = (const float*)d_in[7];
  const float* W2  = (const float*)d_in[8];
  const float* b2  = (const float*)d_in[9];
  const float* g1  = (const float*)d_in[10];
  const float* be1 = (const float*)d_in[11];
  const float* g2  = (const float*)d_in[12];
  const float* be2 = (const float*)d_in[13];
  float* outp = (float*)d_out;

  char* ws = (char*)d_ws;
  u16*   qkvT = (u16*)ws;                       //  6,291,456  [3072,1024] bf16
  u16*   woT  = (u16*)(ws + 6291456);           //  2,097,152
  u16*   w1T  = (u16*)(ws + 8388608);           //  8,388,608  [4096,1024]
  u16*   w2T  = (u16*)(ws + 16777216);          //  8,388,608  [1024,4096]
  float* x2   = (float*)(ws + 25165824);        // 33,554,432  [8192,1024] f32
  u16*   attno= (u16*)(ws + 58720256);          // 16,777,216
  u16*   h2   = (u16*)(ws + 75497472);          // 16,777,216
  u16*   hbf  = (u16*)(ws + 92274688);          // 16,777,216 (LN1 out; dead after QKV GEMM)
  u16*   vtg  = (u16*)(ws + 92274688);          // 16,777,216 Vt (alias hbf; written after)
  u16*   qkvb = (u16*)(ws + 109051904);         // 50,331,648  [8192,3072]
  u16*   ffn1 = (u16*)(ws + 92274688);          // reuse vtg+qkvb region after attention
  (void)in_sizes; (void)n_in; (void)out_size; (void)ws_size;

  // weight conversion
  trans_qkvw<<<dim3(16, 48), 256, 0, stream>>>(Wq, Wk, Wv, qkvT);
  trans_w<<<dim3(16, 16), 256, 0, stream>>>(Wo, woT, 1024, 1024);
  trans_w<<<dim3(64, 16), 256, 0, stream>>>(W1, w1T, 1024, 4096);
  trans_w<<<dim3(16, 64), 256, 0, stream>>>(W2, w2T, 4096, 1024);

  // LN1 -> hbf (bf16)
  ln_kernel<<<2048, 256, 0, stream>>>(x, g1, be1, hbf);
  // QKV projection
  gemm_bt<u16, false, false, false><<<dim3(64, 24), 256, 0, stream>>>(
      hbf, qkvT, qkvb, nullptr, nullptr, 8192, 3072, 1024);
  // V transpose to [bh][64][2048]
  vtrans<<<dim3(32, 64), 256, 0, stream>>>(qkvb, vtg);
  // causal flash attention
  attn_kernel<<<dim3(16, 64), 256, 0, stream>>>(qkvb, vtg, attno);
  // output projection + bias + residual -> x2 (f32)
  gemm_bt<float, false, true, true><<<dim3(64, 8), 256, 0, stream>>>(
      attno, woT, x2, bo, x, 8192, 1024, 1024);
  // LN2 -> h2 (bf16)
  ln_kernel<<<2048, 256, 0, stream>>>(x2, g2, be2, h2);
  // FFN1 + bias + relu -> bf16
  gemm_bt<u16, true, true, false><<<dim3(64, 32), 256, 0, stream>>>(
      h2, w1T, ffn1, b1, nullptr, 8192, 4096, 1024);
  // FFN2 + bias + residual -> d_out (f32)
  gemm_bt<float, false, true, true><<<dim3(64, 8), 256, 0, stream>>>(
      ffn1, w2T, outp, b2, x2, 8192, 1024, 4096);
}

// Round 4
// 551.843 us; speedup vs baseline: 1.2908x; 1.2081x over previous
//
#include <hip/hip_runtime.h>

typedef unsigned short u16;
typedef unsigned int u32;
typedef float f32x4 __attribute__((ext_vector_type(4)));
typedef short s16x8 __attribute__((ext_vector_type(8)));
typedef u16 u16x4 __attribute__((ext_vector_type(4)));
typedef u32 u32x2 __attribute__((ext_vector_type(2)));
typedef u32 u32x4 __attribute__((ext_vector_type(4)));

#define DEVI static __device__ __forceinline__

DEVI u16 f2bf(float f) {
  u32 u = __float_as_uint(f);
  return (u16)((u + 0x7fffu + ((u >> 16) & 1u)) >> 16);
}

DEVI float fexp2(float x) {
#if __has_builtin(__builtin_amdgcn_exp2f)
  return __builtin_amdgcn_exp2f(x);
#else
  return __expf(x * 0.69314718056f);
#endif
}

DEVI void g2l16(const void* g, void* l) {
  __builtin_amdgcn_global_load_lds((const __attribute__((address_space(1))) u32*)g,
                                   (__attribute__((address_space(3))) u32*)l,
                                   16, 0, 0);
}

// ---------------------------------------------------------------------------
// Weight transpose/convert: dst[c*R + r] = bf16(src[r*C + c])
// ---------------------------------------------------------------------------
__global__ __launch_bounds__(256) void trans_w(
    const float* __restrict__ src, u16* __restrict__ dst, int R, int C)
{
  __shared__ __attribute__((aligned(16))) u16 tile[64 * 65];
  const int t = threadIdx.x;
  const int c0 = blockIdx.x * 64, r0 = blockIdx.y * 64;
#pragma unroll
  for (int i = 0; i < 16; ++i) {
    const int idx = i * 256 + t;
    const int c = idx & 63, r = idx >> 6;
    tile[c * 65 + r] = f2bf(src[(long)(r0 + r) * C + c0 + c]);
  }
  __syncthreads();
#pragma unroll
  for (int i = 0; i < 16; ++i) {
    const int idx = i * 256 + t;
    const int r = idx & 63, c = idx >> 6;
    dst[(long)(c0 + c) * R + r0 + r] = tile[c * 65 + r];
  }
}

// QKV weights [H,C,HD] (x3) -> concat B^T layout [3*1024 rows][1024 cols]
__global__ __launch_bounds__(256) void trans_qkvw(
    const float* __restrict__ Wq, const float* __restrict__ Wk,
    const float* __restrict__ Wv, u16* __restrict__ dst)
{
  __shared__ __attribute__((aligned(16))) u16 tile[64 * 65];
  const int t = threadIdx.x;
  const int c0 = blockIdx.x * 64;
  const int mh = blockIdx.y;
  const int mat = mh >> 4, h = mh & 15;
  const float* src = (mat == 0 ? Wq : (mat == 1 ? Wk : Wv)) + (long)h * 65536;
#pragma unroll
  for (int i = 0; i < 16; ++i) {
    const int idx = i * 256 + t;
    const int d = idx & 63, c = idx >> 6;
    tile[d * 65 + c] = f2bf(src[(long)(c0 + c) * 64 + d]);
  }
  __syncthreads();
  const long nb = (long)(mat * 1024 + h * 64);
#pragma unroll
  for (int i = 0; i < 16; ++i) {
    const int idx = i * 256 + t;
    const int d = idx >> 6, c = idx & 63;
    dst[(nb + d) * 1024 + c0 + c] = tile[d * 65 + c];
  }
}

// ---------------------------------------------------------------------------
// V transpose: qkv[B*T,3072] V-part -> Vt[bh][64 d][2048 t] bf16,
// with kv-columns PERMUTED within each 64-t group:
//   col c = g*8+j  holds kv = 2g + 16*(j&3) + (j>>2)
// (must match the attention P-tile column layout; MFMA contraction invariant)
// ---------------------------------------------------------------------------
__global__ __launch_bounds__(256) void vtrans(
    const u16* __restrict__ qkv, u16* __restrict__ vtg)
{
  __shared__ __attribute__((aligned(16))) u32 tile[64 * 33];
  const int t = threadIdx.x;
  const int tt = blockIdx.x, bh = blockIdx.y;
  const long bt0 = (long)(bh >> 4) * 2048;
  const int h = bh & 15;
  const int t0 = tt * 64;
  const int r2 = t >> 3, c8 = t & 7;
  const u16* src = qkv + (bt0 + t0 + 2 * r2) * 3072 + 2048 + h * 64 + c8 * 8;
  const s16x8 a = *(const s16x8*)src;
  const s16x8 b = *(const s16x8*)(src + 3072);
#pragma unroll
  for (int j = 0; j < 8; ++j)
    tile[(c8 * 8 + j) * 33 + r2] = (u32)(u16)a[j] | ((u32)(u16)b[j] << 16);
  __syncthreads();
  // stored col order per 16B group g: [2g,2g+16,2g+32,2g+48, 2g+1,2g+17,2g+33,2g+49]
#pragma unroll
  for (int it = 0; it < 2; ++it) {
    const int idx = it * 256 + t;
    const int d = idx >> 3, g = idx & 7;
    u32 p0 = tile[d * 33 + g];
    u32 p1 = tile[d * 33 + g + 8];
    u32 p2 = tile[d * 33 + g + 16];
    u32 p3 = tile[d * 33 + g + 24];
    u32x4 w;
    w[0] = (p0 & 0xffffu) | (p1 << 16);
    w[1] = (p2 & 0xffffu) | (p3 << 16);
    w[2] = (p0 >> 16) | (p1 & 0xffff0000u);
    w[3] = (p2 >> 16) | (p3 & 0xffff0000u);
    *(u32x4*)(vtg + (long)bh * 131072 + (long)d * 2048 + t0 + g * 8) = w;
  }
}

// ---------------------------------------------------------------------------
// LayerNorm: one wave per 1024-col row, fp32 in -> bf16 out
// ---------------------------------------------------------------------------
__global__ __launch_bounds__(256) void ln_kernel(
    const float* __restrict__ x, const float* __restrict__ g,
    const float* __restrict__ be, u16* __restrict__ out)
{
  const int t = threadIdx.x, wv = t >> 6, l = t & 63;
  const long row = (long)blockIdx.x * 4 + wv;
  const float* xr = x + row * 1024;
  f32x4 v[4];
#pragma unroll
  for (int i = 0; i < 4; ++i) v[i] = *(const f32x4*)(xr + i * 256 + l * 4);
  float s = 0.f, sq = 0.f;
#pragma unroll
  for (int i = 0; i < 4; ++i)
#pragma unroll
    for (int j = 0; j < 4; ++j) { s += v[i][j]; sq += v[i][j] * v[i][j]; }
#pragma unroll
  for (int mask = 1; mask < 64; mask <<= 1) {
    s  += __shfl_xor(s, mask);
    sq += __shfl_xor(sq, mask);
  }
  const float mean = s * (1.f / 1024.f);
  const float var  = sq * (1.f / 1024.f) - mean * mean;
  const float rs = rsqrtf(var + 1e-5f);
#pragma unroll
  for (int i = 0; i < 4; ++i) {
    f32x4 gv = *(const f32x4*)(g  + i * 256 + l * 4);
    f32x4 bv = *(const f32x4*)(be + i * 256 + l * 4);
    u16x4 o;
#pragma unroll
    for (int j = 0; j < 4; ++j) o[j] = f2bf((v[i][j] - mean) * rs * gv[j] + bv[j]);
    *(u16x4*)(out + row * 1024 + i * 256 + l * 4) = o;
  }
}

// ---------------------------------------------------------------------------
// GEMM (m97 structure): C[M,N] = A[M,K] * Bt[N,K]^T, 128x128 tile, BK=32
// ---------------------------------------------------------------------------
template <typename OutT, bool RELU, bool BIAS, bool RESID>
__global__ __launch_bounds__(256) void gemm_bt(
    const u16* __restrict__ A, const u16* __restrict__ Bt,
    OutT* __restrict__ Cout, const float* __restrict__ bias,
    const float* __restrict__ resid, int M, int N, int K)
{
  __shared__ __attribute__((aligned(16))) u16 As[4096];
  __shared__ __attribute__((aligned(16))) u16 Bs[4096];
  const int t  = threadIdx.x;
  const int l  = t & 63;
  const int wv = t >> 6;
  const int lr = l & 15, lg = l >> 4;
  const int wr = wv >> 1, wc = wv & 1;
  const long m0 = (long)blockIdx.x * 128, n0 = (long)blockIdx.y * 128;

  const int srow = t >> 2;
  const int scol = (t & 3) << 3;

  f32x4 acc[4][4] = {};

  const u16* Ap = A  + (m0 + srow) * K + scol;
  const u16* Bp = Bt + (n0 + srow) * K + scol;
  char* Asd = (char*)As + t * 16;
  char* Bsd = (char*)Bs + t * 16;

  for (int k0 = 0; k0 < K; k0 += 32) {
    __syncthreads();
    g2l16(Ap + k0,                Asd);
    g2l16(Ap + (long)64 * K + k0, Asd + 4096);
    g2l16(Bp + k0,                Bsd);
    g2l16(Bp + (long)64 * K + k0, Bsd + 4096);
    __syncthreads();
    s16x8 af[4], bfr[4];
#pragma unroll
    for (int m = 0; m < 4; ++m)
      af[m] = *(const s16x8*)(As + (wr * 64 + m * 16 + lr) * 32 + lg * 8);
#pragma unroll
    for (int n = 0; n < 4; ++n)
      bfr[n] = *(const s16x8*)(Bs + (wc * 64 + n * 16 + lr) * 32 + lg * 8);
#pragma unroll
    for (int m = 0; m < 4; ++m)
#pragma unroll
      for (int n = 0; n < 4; ++n)
        acc[m][n] = __builtin_amdgcn_mfma_f32_16x16x32_bf16(af[m], bfr[n], acc[m][n], 0, 0, 0);
  }

  float bv[4];
#pragma unroll
  for (int n = 0; n < 4; ++n)
    bv[n] = BIAS ? bias[n0 + wc * 64 + n * 16 + lr] : 0.f;

#pragma unroll
  for (int m = 0; m < 4; ++m) {
#pragma unroll
    for (int i = 0; i < 4; ++i) {
      const long row = m0 + wr * 64 + m * 16 + lg * 4 + i;
#pragma unroll
      for (int n = 0; n < 4; ++n) {
        const long col = n0 + wc * 64 + n * 16 + lr;
        float v = acc[m][n][i] + bv[n];
        if (RESID) v += resid[row * N + col];
        if (RELU)  v = fmaxf(v, 0.f);
        if constexpr (sizeof(OutT) == 2) Cout[row * N + col] = f2bf(v);
        else                             Cout[row * N + col] = v;
      }
    }
  }
}

// ---------------------------------------------------------------------------
// Flash attention v3b, causal, 16 heads, HD=64.
// 64-row q-tiles; block processes pair {qte, 31-qte} -> uniform 33 chunks.
// 4 waves x 16 q-rows. KV chunk = 64. K row-major [kv][d]; V pre-transposed
// + kv-col-permuted in vtg. P written as ds_write_b64 (explicit f2bf pairs;
// R3's v_cvt_pk_bf16_f32 asm was the correctness suspect and is removed).
// Softmax: 1/8 folded into exp2 constant; strict defer-max rescale skip.
// ---------------------------------------------------------------------------
__global__ __launch_bounds__(256) void attn_kernel(
    const u16* __restrict__ qkv, const u16* __restrict__ vtg,
    u16* __restrict__ out)
{
  __shared__ __attribute__((aligned(16))) u16 Kl[4096];    // [64 kv][64 d] swz
  __shared__ __attribute__((aligned(16))) u16 Vl[4096];    // [64 d][64 kvperm] swz
  __shared__ __attribute__((aligned(16))) u16 Pl[4][1024]; // per-wave [16 q][64 kvperm] swz

  const float c2 = 0.18033688011112042f;  // 0.125 * log2(e)

  const int t  = threadIdx.x;
  const int wv = t >> 6, l = t & 63;
  const int lr = l & 15, lg = l >> 4;
  const int bh = blockIdx.y;
  const long bt0 = (long)(bh >> 4) * 2048;
  const int h = bh & 15;

  const int r0 = t >> 3, c8 = t & 7;
  const int swc = (c8 ^ (r0 & 7)) << 3;   // pre-swizzled source col
  const u16* ksrc = qkv + (bt0 + r0) * 3072 + 1024 + h * 64 + swc;
  const u16* vsrc = vtg + (long)bh * 131072 + (long)r0 * 2048 + swc;
  char* kd = (char*)Kl + t * 16;
  char* vd = (char*)Vl + t * 16;
  char* pw = (char*)Pl + wv * 2048;

#pragma unroll
  for (int half = 0; half < 2; ++half) {
    const int qte = half ? (31 - (int)blockIdx.x) : (int)blockIdx.x;
    const int qrow0 = qte * 64 + wv * 16;

    s16x8 aq[2];
#pragma unroll
    for (int dc = 0; dc < 2; ++dc)
      aq[dc] = *(const s16x8*)(qkv + (bt0 + qrow0 + lr) * 3072 + h * 64 + dc * 32 + lg * 8);

    f32x4 O[4] = {};
    float mi[4], li[4];
#pragma unroll
    for (int i = 0; i < 4; ++i) { mi[i] = -__builtin_inff(); li[i] = 0.f; }

    for (int scn = 0; scn <= qte; ++scn) {
      const int s0 = scn * 64;
      __syncthreads();
      g2l16(ksrc + (long)s0 * 3072,        kd);
      g2l16(ksrc + (long)(s0 + 32) * 3072, kd + 4096);
      g2l16(vsrc + s0,                     vd);
      g2l16(vsrc + s0 + 65536,             vd + 4096);
      __syncthreads();

      // K fragments (B-operand): [kv-tile][d-half]
      s16x8 kf[4][2];
#pragma unroll
      for (int n = 0; n < 4; ++n) {
        const int row = n * 16 + lr;
        const int sw = (row & 7) << 4;
#pragma unroll
        for (int dh = 0; dh < 2; ++dh)
          kf[n][dh] = *(const s16x8*)((const char*)Kl + row * 128 +
                                      (((dh * 4 + lg) << 4) ^ sw));
      }

      f32x4 S[4];
#pragma unroll
      for (int n = 0; n < 4; ++n) {
        f32x4 z = {};
        z = __builtin_amdgcn_mfma_f32_16x16x32_bf16(aq[0], kf[n][0], z, 0, 0, 0);
        S[n] = __builtin_amdgcn_mfma_f32_16x16x32_bf16(aq[1], kf[n][1], z, 0, 0, 0);
      }

      float mt[4];
      if (scn == qte) {  // diagonal chunk: causal mask (raw S, -inf)
#pragma unroll
        for (int i = 0; i < 4; ++i) {
          const int qg = qrow0 + lg * 4 + i;
#pragma unroll
          for (int n = 0; n < 4; ++n)
            S[n][i] = (s0 + n * 16 + lr <= qg) ? S[n][i] : -__builtin_inff();
          mt[i] = fmaxf(fmaxf(S[0][i], S[1][i]), fmaxf(S[2][i], S[3][i]));
        }
      } else {
#pragma unroll
        for (int i = 0; i < 4; ++i)
          mt[i] = fmaxf(fmaxf(S[0][i], S[1][i]), fmaxf(S[2][i], S[3][i]));
      }
#pragma unroll
      for (int msk = 1; msk < 16; msk <<= 1)
#pragma unroll
        for (int i = 0; i < 4; ++i)
          mt[i] = fmaxf(mt[i], __shfl_xor(mt[i], msk));

      // defer-max: skip rescale pass when no lane's max grew (exact)
      const int grow = (mt[0] > mi[0]) | (mt[1] > mi[1]) |
                       (mt[2] > mi[2]) | (mt[3] > mi[3]);
      if (__any(grow)) {
#pragma unroll
        for (int i = 0; i < 4; ++i) {
          const float mn = fmaxf(mi[i], mt[i]);
          const float so = fexp2((mi[i] - mn) * c2);
          mi[i] = mn;
          li[i] *= so;
#pragma unroll
          for (int n = 0; n < 4; ++n) O[n][i] *= so;
        }
      }

      // P = exp2(c2*(S - mi)) -> bf16 pairs (explicit f2bf pack) -> ds_write_b64
#pragma unroll
      for (int i = 0; i < 4; ++i) {
        const float nmc = -mi[i] * c2;
        float p[4];
#pragma unroll
        for (int n = 0; n < 4; ++n) p[n] = fexp2(fmaf(S[n][i], c2, nmc));
        li[i] += (p[0] + p[1]) + (p[2] + p[3]);
        const int q_l = lg * 4 + i;
        u32x2 pk;
        pk[0] = (u32)f2bf(p[0]) | ((u32)f2bf(p[1]) << 16);
        pk[1] = (u32)f2bf(p[2]) | ((u32)f2bf(p[3]) << 16);
        *(u32x2*)(pw + q_l * 128 + ((((lr >> 1) << 4) ^ ((q_l & 7) << 4)) + ((lr & 1) << 3))) = pk;
      }

      // V fragments (B-operand, kv-permuted cols): [d-tile][kv-half]
      s16x8 vf[4][2];
#pragma unroll
      for (int dn = 0; dn < 4; ++dn) {
        const int row = dn * 16 + lr;
        const int sw = (row & 7) << 4;
#pragma unroll
        for (int kk = 0; kk < 2; ++kk)
          vf[dn][kk] = *(const s16x8*)((const char*)Vl + row * 128 +
                                       (((kk * 4 + lg) << 4) ^ sw));
      }
      // P fragments (A-operand): row = lr
      s16x8 pa[2];
#pragma unroll
      for (int kk = 0; kk < 2; ++kk)
        pa[kk] = *(const s16x8*)(pw + lr * 128 + (((kk * 4 + lg) << 4) ^ ((lr & 7) << 4)));
#pragma unroll
      for (int dn = 0; dn < 4; ++dn) {
        O[dn] = __builtin_amdgcn_mfma_f32_16x16x32_bf16(pa[0], vf[dn][0], O[dn], 0, 0, 0);
        O[dn] = __builtin_amdgcn_mfma_f32_16x16x32_bf16(pa[1], vf[dn][1], O[dn], 0, 0, 0);
      }
    }

#pragma unroll
    for (int msk = 1; msk < 16; msk <<= 1)
#pragma unroll
      for (int i = 0; i < 4; ++i)
        li[i] += __shfl_xor(li[i], msk);

#pragma unroll
    for (int i = 0; i < 4; ++i) {
      const float rl = 1.f / li[i];
      const long ob = (bt0 + qrow0 + lg * 4 + i) * 1024 + h * 64 + lr;
#pragma unroll
      for (int n = 0; n < 4; ++n)
        out[ob + n * 16] = f2bf(O[n][i] * rl);
    }
  }
}

// ---------------------------------------------------------------------------
extern "C" void kernel_launch(void* const* d_in, const int* in_sizes, int n_in,
                              void* d_out, int out_size, void* d_ws, size_t ws_size,
                              hipStream_t stream)
{
  const float* x   = (const float*)d_in[0];
  const float* Wq  = (const float*)d_in[1];
  const float* Wk  = (const float*)d_in[2];
  const float* Wv  = (const float*)d_in[3];
  const float* Wo  = (const float*)d_in[4];
  const float* bo  = (const float*)d_in[5];
  const float* W1  = (const float*)d_in[6];
  const float* b1  = (const float*)d_in[7];
  const float* W2  = (const float*)d_in[8];
  const float* b2  = (const float*)d_in[9];
  const float* g1  = (const float*)d_in[10];
  const float* be1 = (const float*)d_in[11];
  const float* g2  = (const float*)d_in[12];
  const float* be2 = (const float*)d_in[13];
  float* outp = (float*)d_out;

  char* ws = (char*)d_ws;
  u16*   qkvT = (u16*)ws;                       //  6,291,456  [3072,1024] bf16
  u16*   woT  = (u16*)(ws + 6291456);           //  2,097,152
  u16*   w1T  = (u16*)(ws + 8388608);           //  8,388,608  [4096,1024]
  u16*   w2T  = (u16*)(ws + 16777216);          //  8,388,608  [1024,4096]
  float* x2   = (float*)(ws + 25165824);        // 33,554,432  [8192,1024] f32
  u16*   attno= (u16*)(ws + 58720256);          // 16,777,216
  u16*   h2   = (u16*)(ws + 75497472);          // 16,777,216
  u16*   hbf  = (u16*)(ws + 92274688);          // 16,777,216 (LN1 out; dead after QKV GEMM)
  u16*   vtg  = (u16*)(ws + 92274688);          // 16,777,216 Vt (alias hbf; written after)
  u16*   qkvb = (u16*)(ws + 109051904);         // 50,331,648  [8192,3072]
  u16*   ffn1 = (u16*)(ws + 92274688);          // reuse vtg+qkvb region after attention
  (void)in_sizes; (void)n_in; (void)out_size; (void)ws_size;

  // weight conversion
  trans_qkvw<<<dim3(16, 48), 256, 0, stream>>>(Wq, Wk, Wv, qkvT);
  trans_w<<<dim3(16, 16), 256, 0, stream>>>(Wo, woT, 1024, 1024);
  trans_w<<<dim3(64, 16), 256, 0, stream>>>(W1, w1T, 1024, 4096);
  trans_w<<<dim3(16, 64), 256, 0, stream>>>(W2, w2T, 4096, 1024);

  // LN1 -> hbf (bf16)
  ln_kernel<<<2048, 256, 0, stream>>>(x, g1, be1, hbf);
  // QKV projection
  gemm_bt<u16, false, false, false><<<dim3(64, 24), 256, 0, stream>>>(
      hbf, qkvT, qkvb, nullptr, nullptr, 8192, 3072, 1024);
  // V transpose (kv-permuted) to [bh][64][2048]
  vtrans<<<dim3(32, 64), 256, 0, stream>>>(qkvb, vtg);
  // causal flash attention
  attn_kernel<<<dim3(16, 64), 256, 0, stream>>>(qkvb, vtg, attno);
  // output projection + bias + residual -> x2 (f32)
  gemm_bt<float, false, true, true><<<dim3(64, 8), 256, 0, stream>>>(
      attno, woT, x2, bo, x, 8192, 1024, 1024);
  // LN2 -> h2 (bf16)
  ln_kernel<<<2048, 256, 0, stream>>>(x2, g2, be2, h2);
  // FFN1 + bias + relu -> bf16
  gemm_bt<u16, true, true, false><<<dim3(64, 32), 256, 0, stream>>>(
      h2, w1T, ffn1, b1, nullptr, 8192, 4096, 1024);
  // FFN2 + bias + residual -> d_out (f32)
  gemm_bt<float, false, true, true><<<dim3(64, 8), 256, 0, stream>>>(
      ffn1, w2T, outp, b2, x2, 8192, 1024, 4096);
}

// Round 5
// 517.135 us; speedup vs baseline: 1.3774x; 1.0671x over previous
//
#include <hip/hip_runtime.h>

typedef unsigned short u16;
typedef unsigned int u32;
typedef float f32x4 __attribute__((ext_vector_type(4)));
typedef short s16x8 __attribute__((ext_vector_type(8)));
typedef u16 u16x4 __attribute__((ext_vector_type(4)));
typedef u32 u32x2 __attribute__((ext_vector_type(2)));
typedef u32 u32x4 __attribute__((ext_vector_type(4)));

#define DEVI static __device__ __forceinline__

DEVI u16 f2bf(float f) {
  u32 u = __float_as_uint(f);
  return (u16)((u + 0x7fffu + ((u >> 16) & 1u)) >> 16);
}

DEVI float fexp2(float x) {
#if __has_builtin(__builtin_amdgcn_exp2f)
  return __builtin_amdgcn_exp2f(x);
#else
  return __expf(x * 0.69314718056f);
#endif
}

DEVI void g2l16(const void* g, void* l) {
  __builtin_amdgcn_global_load_lds((const __attribute__((address_space(1))) u32*)g,
                                   (__attribute__((address_space(3))) u32*)l,
                                   16, 0, 0);
}

// ---------------------------------------------------------------------------
// Weight transpose/convert: dst[c*R + r] = bf16(src[r*C + c])
// ---------------------------------------------------------------------------
__global__ __launch_bounds__(256) void trans_w(
    const float* __restrict__ src, u16* __restrict__ dst, int R, int C)
{
  __shared__ __attribute__((aligned(16))) u16 tile[64 * 65];
  const int t = threadIdx.x;
  const int c0 = blockIdx.x * 64, r0 = blockIdx.y * 64;
#pragma unroll
  for (int i = 0; i < 16; ++i) {
    const int idx = i * 256 + t;
    const int c = idx & 63, r = idx >> 6;
    tile[c * 65 + r] = f2bf(src[(long)(r0 + r) * C + c0 + c]);
  }
  __syncthreads();
#pragma unroll
  for (int i = 0; i < 16; ++i) {
    const int idx = i * 256 + t;
    const int r = idx & 63, c = idx >> 6;
    dst[(long)(c0 + c) * R + r0 + r] = tile[c * 65 + r];
  }
}

// QKV weights [H,C,HD] (x3) -> concat B^T layout [3*1024 rows][1024 cols]
__global__ __launch_bounds__(256) void trans_qkvw(
    const float* __restrict__ Wq, const float* __restrict__ Wk,
    const float* __restrict__ Wv, u16* __restrict__ dst)
{
  __shared__ __attribute__((aligned(16))) u16 tile[64 * 65];
  const int t = threadIdx.x;
  const int c0 = blockIdx.x * 64;
  const int mh = blockIdx.y;
  const int mat = mh >> 4, h = mh & 15;
  const float* src = (mat == 0 ? Wq : (mat == 1 ? Wk : Wv)) + (long)h * 65536;
#pragma unroll
  for (int i = 0; i < 16; ++i) {
    const int idx = i * 256 + t;
    const int d = idx & 63, c = idx >> 6;
    tile[d * 65 + c] = f2bf(src[(long)(c0 + c) * 64 + d]);
  }
  __syncthreads();
  const long nb = (long)(mat * 1024 + h * 64);
#pragma unroll
  for (int i = 0; i < 16; ++i) {
    const int idx = i * 256 + t;
    const int d = idx >> 6, c = idx & 63;
    dst[(nb + d) * 1024 + c0 + c] = tile[d * 65 + c];
  }
}

// ---------------------------------------------------------------------------
// V transpose: qkv[B*T,3072] V-part -> Vt[bh][64 d][2048 t] bf16,
// with kv-columns PERMUTED within each 64-t group:
//   col c = g*8+j  holds kv = 2g + 16*(j&3) + (j>>2)
// (must match the attention P-tile column layout; MFMA contraction invariant)
// ---------------------------------------------------------------------------
__global__ __launch_bounds__(256) void vtrans(
    const u16* __restrict__ qkv, u16* __restrict__ vtg)
{
  __shared__ __attribute__((aligned(16))) u32 tile[64 * 33];
  const int t = threadIdx.x;
  const int tt = blockIdx.x, bh = blockIdx.y;
  const long bt0 = (long)(bh >> 4) * 2048;
  const int h = bh & 15;
  const int t0 = tt * 64;
  const int r2 = t >> 3, c8 = t & 7;
  const u16* src = qkv + (bt0 + t0 + 2 * r2) * 3072 + 2048 + h * 64 + c8 * 8;
  const s16x8 a = *(const s16x8*)src;
  const s16x8 b = *(const s16x8*)(src + 3072);
#pragma unroll
  for (int j = 0; j < 8; ++j)
    tile[(c8 * 8 + j) * 33 + r2] = (u32)(u16)a[j] | ((u32)(u16)b[j] << 16);
  __syncthreads();
  // stored col order per 16B group g: [2g,2g+16,2g+32,2g+48, 2g+1,2g+17,2g+33,2g+49]
#pragma unroll
  for (int it = 0; it < 2; ++it) {
    const int idx = it * 256 + t;
    const int d = idx >> 3, g = idx & 7;
    u32 p0 = tile[d * 33 + g];
    u32 p1 = tile[d * 33 + g + 8];
    u32 p2 = tile[d * 33 + g + 16];
    u32 p3 = tile[d * 33 + g + 24];
    u32x4 w;
    w[0] = (p0 & 0xffffu) | (p1 << 16);
    w[1] = (p2 & 0xffffu) | (p3 << 16);
    w[2] = (p0 >> 16) | (p1 & 0xffff0000u);
    w[3] = (p2 >> 16) | (p3 & 0xffff0000u);
    *(u32x4*)(vtg + (long)bh * 131072 + (long)d * 2048 + t0 + g * 8) = w;
  }
}

// ---------------------------------------------------------------------------
// LayerNorm: one wave per 1024-col row, fp32 in -> bf16 out
// ---------------------------------------------------------------------------
__global__ __launch_bounds__(256) void ln_kernel(
    const float* __restrict__ x, const float* __restrict__ g,
    const float* __restrict__ be, u16* __restrict__ out)
{
  const int t = threadIdx.x, wv = t >> 6, l = t & 63;
  const long row = (long)blockIdx.x * 4 + wv;
  const float* xr = x + row * 1024;
  f32x4 v[4];
#pragma unroll
  for (int i = 0; i < 4; ++i) v[i] = *(const f32x4*)(xr + i * 256 + l * 4);
  float s = 0.f, sq = 0.f;
#pragma unroll
  for (int i = 0; i < 4; ++i)
#pragma unroll
    for (int j = 0; j < 4; ++j) { s += v[i][j]; sq += v[i][j] * v[i][j]; }
#pragma unroll
  for (int mask = 1; mask < 64; mask <<= 1) {
    s  += __shfl_xor(s, mask);
    sq += __shfl_xor(sq, mask);
  }
  const float mean = s * (1.f / 1024.f);
  const float var  = sq * (1.f / 1024.f) - mean * mean;
  const float rs = rsqrtf(var + 1e-5f);
#pragma unroll
  for (int i = 0; i < 4; ++i) {
    f32x4 gv = *(const f32x4*)(g  + i * 256 + l * 4);
    f32x4 bv = *(const f32x4*)(be + i * 256 + l * 4);
    u16x4 o;
#pragma unroll
    for (int j = 0; j < 4; ++j) o[j] = f2bf((v[i][j] - mean) * rs * gv[j] + bv[j]);
    *(u16x4*)(out + row * 1024 + i * 256 + l * 4) = o;
  }
}

// ---------------------------------------------------------------------------
// GEMM v2: C[M,N] = A[M,K] * Bt[N,K]^T, 128x128 tile, BK=64,
// XOR-swizzled LDS (pre-swizzled global_load_lds source + swizzled b128
// reads -> conflict-free), double-buffered 2-phase: one barrier per K-tile.
// ---------------------------------------------------------------------------
template <typename OutT, bool RELU, bool BIAS, bool RESID>
__global__ __launch_bounds__(256) void gemm_bt(
    const u16* __restrict__ A, const u16* __restrict__ Bt,
    OutT* __restrict__ Cout, const float* __restrict__ bias,
    const float* __restrict__ resid, int M, int N, int K)
{
  __shared__ __attribute__((aligned(16))) u16 As[2][8192];  // [128 m][64 k] swz
  __shared__ __attribute__((aligned(16))) u16 Bs[2][8192];  // [128 n][64 k] swz
  const int t  = threadIdx.x;
  const int l  = t & 63;
  const int wv = t >> 6;
  const int lr = l & 15, lg = l >> 4;
  const int wr = wv >> 1, wc = wv & 1;
  const long m0 = (long)blockIdx.x * 128, n0 = (long)blockIdx.y * 128;

  f32x4 acc[4][4] = {};

  // staging: chunk c = i*256+t -> LDS byte c*16 = row (c>>3) * 128 + slot (c&7)*16
  // slot s holds global col-group g = s ^ (row&7); (i*32)%8==0 so swizzle is i-invariant
  const int srow8 = t >> 3;
  const int swc = ((t & 7) ^ (srow8 & 7)) << 3;
  const u16* Ap = A  + (m0 + srow8) * K + swc;
  const u16* Bp = Bt + (n0 + srow8) * K + swc;

#define GSTAGE(buf, kof)                                                      \
  {                                                                           \
    _Pragma("unroll")                                                         \
    for (int i = 0; i < 4; ++i) {                                             \
      g2l16(Ap + (long)i * 32 * K + (kof), (char*)As[buf] + (i * 256 + t) * 16); \
      g2l16(Bp + (long)i * 32 * K + (kof), (char*)Bs[buf] + (i * 256 + t) * 16); \
    }                                                                         \
  }

#define GCOMPUTE(buf)                                                         \
  {                                                                           \
    const char* Ab = (const char*)As[buf];                                    \
    const char* Bb = (const char*)Bs[buf];                                    \
    _Pragma("unroll")                                                         \
    for (int kk = 0; kk < 2; ++kk) {                                          \
      s16x8 af[4], bfr[4];                                                    \
      _Pragma("unroll")                                                       \
      for (int m = 0; m < 4; ++m) {                                           \
        const int row = wr * 64 + m * 16 + lr;                                \
        af[m] = *(const s16x8*)(Ab + row * 128 +                              \
                                ((((kk * 4 + lg) << 4) ^ ((row & 7) << 4)))); \
      }                                                                       \
      _Pragma("unroll")                                                       \
      for (int n = 0; n < 4; ++n) {                                           \
        const int row = wc * 64 + n * 16 + lr;                                \
        bfr[n] = *(const s16x8*)(Bb + row * 128 +                             \
                                 ((((kk * 4 + lg) << 4) ^ ((row & 7) << 4))));\
      }                                                                       \
      _Pragma("unroll")                                                       \
      for (int m = 0; m < 4; ++m)                                             \
        _Pragma("unroll")                                                     \
        for (int n = 0; n < 4; ++n)                                           \
          acc[m][n] = __builtin_amdgcn_mfma_f32_16x16x32_bf16(af[m], bfr[n],  \
                                                              acc[m][n], 0, 0, 0); \
    }                                                                         \
  }

  const int nt = K >> 6;
  GSTAGE(0, 0);
  __syncthreads();
  int cur = 0;
  for (int tt = 0; tt < nt - 1; ++tt) {
    GSTAGE(cur ^ 1, (tt + 1) * 64);
    GCOMPUTE(cur);
    __syncthreads();   // drains this wave's vmcnt (stage) + lgkm, then barrier
    cur ^= 1;
  }
  GCOMPUTE(cur);
#undef GSTAGE
#undef GCOMPUTE

  float bv[4];
#pragma unroll
  for (int n = 0; n < 4; ++n)
    bv[n] = BIAS ? bias[n0 + wc * 64 + n * 16 + lr] : 0.f;

#pragma unroll
  for (int m = 0; m < 4; ++m) {
#pragma unroll
    for (int i = 0; i < 4; ++i) {
      const long row = m0 + wr * 64 + m * 16 + lg * 4 + i;
#pragma unroll
      for (int n = 0; n < 4; ++n) {
        const long col = n0 + wc * 64 + n * 16 + lr;
        float v = acc[m][n][i] + bv[n];
        if (RESID) v += resid[row * N + col];
        if (RELU)  v = fmaxf(v, 0.f);
        if constexpr (sizeof(OutT) == 2) Cout[row * N + col] = f2bf(v);
        else                             Cout[row * N + col] = v;
      }
    }
  }
}

// ---------------------------------------------------------------------------
// Flash attention v3b, causal, 16 heads, HD=64.
// 64-row q-tiles; block processes pair {qte, 31-qte} -> uniform 33 chunks.
// 4 waves x 16 q-rows. KV chunk = 64. K row-major [kv][d]; V pre-transposed
// + kv-col-permuted in vtg. P written as ds_write_b64 (explicit f2bf pairs).
// Softmax: 1/8 folded into exp2 constant; strict defer-max rescale skip.
// ---------------------------------------------------------------------------
__global__ __launch_bounds__(256) void attn_kernel(
    const u16* __restrict__ qkv, const u16* __restrict__ vtg,
    u16* __restrict__ out)
{
  __shared__ __attribute__((aligned(16))) u16 Kl[4096];    // [64 kv][64 d] swz
  __shared__ __attribute__((aligned(16))) u16 Vl[4096];    // [64 d][64 kvperm] swz
  __shared__ __attribute__((aligned(16))) u16 Pl[4][1024]; // per-wave [16 q][64 kvperm] swz

  const float c2 = 0.18033688011112042f;  // 0.125 * log2(e)

  const int t  = threadIdx.x;
  const int wv = t >> 6, l = t & 63;
  const int lr = l & 15, lg = l >> 4;
  const int bh = blockIdx.y;
  const long bt0 = (long)(bh >> 4) * 2048;
  const int h = bh & 15;

  const int r0 = t >> 3, c8 = t & 7;
  const int swc = (c8 ^ (r0 & 7)) << 3;   // pre-swizzled source col
  const u16* ksrc = qkv + (bt0 + r0) * 3072 + 1024 + h * 64 + swc;
  const u16* vsrc = vtg + (long)bh * 131072 + (long)r0 * 2048 + swc;
  char* kd = (char*)Kl + t * 16;
  char* vd = (char*)Vl + t * 16;
  char* pw = (char*)Pl + wv * 2048;

#pragma unroll
  for (int half = 0; half < 2; ++half) {
    const int qte = half ? (31 - (int)blockIdx.x) : (int)blockIdx.x;
    const int qrow0 = qte * 64 + wv * 16;

    s16x8 aq[2];
#pragma unroll
    for (int dc = 0; dc < 2; ++dc)
      aq[dc] = *(const s16x8*)(qkv + (bt0 + qrow0 + lr) * 3072 + h * 64 + dc * 32 + lg * 8);

    f32x4 O[4] = {};
    float mi[4], li[4];
#pragma unroll
    for (int i = 0; i < 4; ++i) { mi[i] = -__builtin_inff(); li[i] = 0.f; }

    for (int scn = 0; scn <= qte; ++scn) {
      const int s0 = scn * 64;
      __syncthreads();
      g2l16(ksrc + (long)s0 * 3072,        kd);
      g2l16(ksrc + (long)(s0 + 32) * 3072, kd + 4096);
      g2l16(vsrc + s0,                     vd);
      g2l16(vsrc + s0 + 65536,             vd + 4096);
      __syncthreads();

      // K fragments (B-operand): [kv-tile][d-half]
      s16x8 kf[4][2];
#pragma unroll
      for (int n = 0; n < 4; ++n) {
        const int row = n * 16 + lr;
        const int sw = (row & 7) << 4;
#pragma unroll
        for (int dh = 0; dh < 2; ++dh)
          kf[n][dh] = *(const s16x8*)((const char*)Kl + row * 128 +
                                      (((dh * 4 + lg) << 4) ^ sw));
      }

      f32x4 S[4];
#pragma unroll
      for (int n = 0; n < 4; ++n) {
        f32x4 z = {};
        z = __builtin_amdgcn_mfma_f32_16x16x32_bf16(aq[0], kf[n][0], z, 0, 0, 0);
        S[n] = __builtin_amdgcn_mfma_f32_16x16x32_bf16(aq[1], kf[n][1], z, 0, 0, 0);
      }

      float mt[4];
      if (scn == qte) {  // diagonal chunk: causal mask (raw S, -inf)
#pragma unroll
        for (int i = 0; i < 4; ++i) {
          const int qg = qrow0 + lg * 4 + i;
#pragma unroll
          for (int n = 0; n < 4; ++n)
            S[n][i] = (s0 + n * 16 + lr <= qg) ? S[n][i] : -__builtin_inff();
          mt[i] = fmaxf(fmaxf(S[0][i], S[1][i]), fmaxf(S[2][i], S[3][i]));
        }
      } else {
#pragma unroll
        for (int i = 0; i < 4; ++i)
          mt[i] = fmaxf(fmaxf(S[0][i], S[1][i]), fmaxf(S[2][i], S[3][i]));
      }
#pragma unroll
      for (int msk = 1; msk < 16; msk <<= 1)
#pragma unroll
        for (int i = 0; i < 4; ++i)
          mt[i] = fmaxf(mt[i], __shfl_xor(mt[i], msk));

      // defer-max: skip rescale pass when no lane's max grew (exact)
      const int grow = (mt[0] > mi[0]) | (mt[1] > mi[1]) |
                       (mt[2] > mi[2]) | (mt[3] > mi[3]);
      if (__any(grow)) {
#pragma unroll
        for (int i = 0; i < 4; ++i) {
          const float mn = fmaxf(mi[i], mt[i]);
          const float so = fexp2((mi[i] - mn) * c2);
          mi[i] = mn;
          li[i] *= so;
#pragma unroll
          for (int n = 0; n < 4; ++n) O[n][i] *= so;
        }
      }

      // P = exp2(c2*(S - mi)) -> bf16 pairs (explicit f2bf pack) -> ds_write_b64
#pragma unroll
      for (int i = 0; i < 4; ++i) {
        const float nmc = -mi[i] * c2;
        float p[4];
#pragma unroll
        for (int n = 0; n < 4; ++n) p[n] = fexp2(fmaf(S[n][i], c2, nmc));
        li[i] += (p[0] + p[1]) + (p[2] + p[3]);
        const int q_l = lg * 4 + i;
        u32x2 pk;
        pk[0] = (u32)f2bf(p[0]) | ((u32)f2bf(p[1]) << 16);
        pk[1] = (u32)f2bf(p[2]) | ((u32)f2bf(p[3]) << 16);
        *(u32x2*)(pw + q_l * 128 + ((((lr >> 1) << 4) ^ ((q_l & 7) << 4)) + ((lr & 1) << 3))) = pk;
      }

      // V fragments (B-operand, kv-permuted cols): [d-tile][kv-half]
      s16x8 vf[4][2];
#pragma unroll
      for (int dn = 0; dn < 4; ++dn) {
        const int row = dn * 16 + lr;
        const int sw = (row & 7) << 4;
#pragma unroll
        for (int kk = 0; kk < 2; ++kk)
          vf[dn][kk] = *(const s16x8*)((const char*)Vl + row * 128 +
                                       (((kk * 4 + lg) << 4) ^ sw));
      }
      // P fragments (A-operand): row = lr
      s16x8 pa[2];
#pragma unroll
      for (int kk = 0; kk < 2; ++kk)
        pa[kk] = *(const s16x8*)(pw + lr * 128 + (((kk * 4 + lg) << 4) ^ ((lr & 7) << 4)));
#pragma unroll
      for (int dn = 0; dn < 4; ++dn) {
        O[dn] = __builtin_amdgcn_mfma_f32_16x16x32_bf16(pa[0], vf[dn][0], O[dn], 0, 0, 0);
        O[dn] = __builtin_amdgcn_mfma_f32_16x16x32_bf16(pa[1], vf[dn][1], O[dn], 0, 0, 0);
      }
    }

#pragma unroll
    for (int msk = 1; msk < 16; msk <<= 1)
#pragma unroll
      for (int i = 0; i < 4; ++i)
        li[i] += __shfl_xor(li[i], msk);

#pragma unroll
    for (int i = 0; i < 4; ++i) {
      const float rl = 1.f / li[i];
      const long ob = (bt0 + qrow0 + lg * 4 + i) * 1024 + h * 64 + lr;
#pragma unroll
      for (int n = 0; n < 4; ++n)
        out[ob + n * 16] = f2bf(O[n][i] * rl);
    }
  }
}

// ---------------------------------------------------------------------------
extern "C" void kernel_launch(void* const* d_in, const int* in_sizes, int n_in,
                              void* d_out, int out_size, void* d_ws, size_t ws_size,
                              hipStream_t stream)
{
  const float* x   = (const float*)d_in[0];
  const float* Wq  = (const float*)d_in[1];
  const float* Wk  = (const float*)d_in[2];
  const float* Wv  = (const float*)d_in[3];
  const float* Wo  = (const float*)d_in[4];
  const float* bo  = (const float*)d_in[5];
  const float* W1  = (const float*)d_in[6];
  const float* b1  = (const float*)d_in[7];
  const float* W2  = (const float*)d_in[8];
  const float* b2  = (const float*)d_in[9];
  const float* g1  = (const float*)d_in[10];
  const float* be1 = (const float*)d_in[11];
  const float* g2  = (const float*)d_in[12];
  const float* be2 = (const float*)d_in[13];
  float* outp = (float*)d_out;

  char* ws = (char*)d_ws;
  u16*   qkvT = (u16*)ws;                       //  6,291,456  [3072,1024] bf16
  u16*   woT  = (u16*)(ws + 6291456);           //  2,097,152
  u16*   w1T  = (u16*)(ws + 8388608);           //  8,388,608  [4096,1024]
  u16*   w2T  = (u16*)(ws + 16777216);          //  8,388,608  [1024,4096]
  float* x2   = (float*)(ws + 25165824);        // 33,554,432  [8192,1024] f32
  u16*   attno= (u16*)(ws + 58720256);          // 16,777,216
  u16*   h2   = (u16*)(ws + 75497472);          // 16,777,216
  u16*   hbf  = (u16*)(ws + 92274688);          // 16,777,216 (LN1 out; dead after QKV GEMM)
  u16*   vtg  = (u16*)(ws + 92274688);          // 16,777,216 Vt (alias hbf; written after)
  u16*   qkvb = (u16*)(ws + 109051904);         // 50,331,648  [8192,3072]
  u16*   ffn1 = (u16*)(ws + 92274688);          // reuse vtg+qkvb region after attention
  (void)in_sizes; (void)n_in; (void)out_size; (void)ws_size;

  // weight conversion
  trans_qkvw<<<dim3(16, 48), 256, 0, stream>>>(Wq, Wk, Wv, qkvT);
  trans_w<<<dim3(16, 16), 256, 0, stream>>>(Wo, woT, 1024, 1024);
  trans_w<<<dim3(64, 16), 256, 0, stream>>>(W1, w1T, 1024, 4096);
  trans_w<<<dim3(16, 64), 256, 0, stream>>>(W2, w2T, 4096, 1024);

  // LN1 -> hbf (bf16)
  ln_kernel<<<2048, 256, 0, stream>>>(x, g1, be1, hbf);
  // QKV projection
  gemm_bt<u16, false, false, false><<<dim3(64, 24), 256, 0, stream>>>(
      hbf, qkvT, qkvb, nullptr, nullptr, 8192, 3072, 1024);
  // V transpose (kv-permuted) to [bh][64][2048]
  vtrans<<<dim3(32, 64), 256, 0, stream>>>(qkvb, vtg);
  // causal flash attention
  attn_kernel<<<dim3(16, 64), 256, 0, stream>>>(qkvb, vtg, attno);
  // output projection + bias + residual -> x2 (f32)
  gemm_bt<float, false, true, true><<<dim3(64, 8), 256, 0, stream>>>(
      attno, woT, x2, bo, x, 8192, 1024, 1024);
  // LN2 -> h2 (bf16)
  ln_kernel<<<2048, 256, 0, stream>>>(x2, g2, be2, h2);
  // FFN1 + bias + relu -> bf16
  gemm_bt<u16, true, true, false><<<dim3(64, 32), 256, 0, stream>>>(
      h2, w1T, ffn1, b1, nullptr, 8192, 4096, 1024);
  // FFN2 + bias + residual -> d_out (f32)
  gemm_bt<float, false, true, true><<<dim3(64, 8), 256, 0, stream>>>(
      ffn1, w2T, outp, b2, x2, 8192, 1024, 4096);
}

// Round 6
// 517.115 us; speedup vs baseline: 1.3774x; 1.0000x over previous
//
#include <hip/hip_runtime.h>

typedef unsigned short u16;
typedef unsigned int u32;
typedef float f32x4 __attribute__((ext_vector_type(4)));
typedef short s16x8 __attribute__((ext_vector_type(8)));
typedef u16 u16x4 __attribute__((ext_vector_type(4)));
typedef u32 u32x2 __attribute__((ext_vector_type(2)));
typedef u32 u32x4 __attribute__((ext_vector_type(4)));

#define DEVI static __device__ __forceinline__

DEVI u16 f2bf(float f) {
  u32 u = __float_as_uint(f);
  return (u16)((u + 0x7fffu + ((u >> 16) & 1u)) >> 16);
}

DEVI float fexp2(float x) {
#if __has_builtin(__builtin_amdgcn_exp2f)
  return __builtin_amdgcn_exp2f(x);
#else
  return __expf(x * 0.69314718056f);
#endif
}

DEVI void g2l16(const void* g, void* l) {
  __builtin_amdgcn_global_load_lds((const __attribute__((address_space(1))) u32*)g,
                                   (__attribute__((address_space(3))) u32*)l,
                                   16, 0, 0);
}

// ---------------------------------------------------------------------------
// Weight transpose/convert: dst[c*R + r] = bf16(src[r*C + c])
// ---------------------------------------------------------------------------
__global__ __launch_bounds__(256) void trans_w(
    const float* __restrict__ src, u16* __restrict__ dst, int R, int C)
{
  __shared__ __attribute__((aligned(16))) u16 tile[64 * 65];
  const int t = threadIdx.x;
  const int c0 = blockIdx.x * 64, r0 = blockIdx.y * 64;
#pragma unroll
  for (int i = 0; i < 16; ++i) {
    const int idx = i * 256 + t;
    const int c = idx & 63, r = idx >> 6;
    tile[c * 65 + r] = f2bf(src[(long)(r0 + r) * C + c0 + c]);
  }
  __syncthreads();
#pragma unroll
  for (int i = 0; i < 16; ++i) {
    const int idx = i * 256 + t;
    const int r = idx & 63, c = idx >> 6;
    dst[(long)(c0 + c) * R + r0 + r] = tile[c * 65 + r];
  }
}

// QKV weights [H,C,HD] (x3) -> concat B^T layout [3*1024 rows][1024 cols]
__global__ __launch_bounds__(256) void trans_qkvw(
    const float* __restrict__ Wq, const float* __restrict__ Wk,
    const float* __restrict__ Wv, u16* __restrict__ dst)
{
  __shared__ __attribute__((aligned(16))) u16 tile[64 * 65];
  const int t = threadIdx.x;
  const int c0 = blockIdx.x * 64;
  const int mh = blockIdx.y;
  const int mat = mh >> 4, h = mh & 15;
  const float* src = (mat == 0 ? Wq : (mat == 1 ? Wk : Wv)) + (long)h * 65536;
#pragma unroll
  for (int i = 0; i < 16; ++i) {
    const int idx = i * 256 + t;
    const int d = idx & 63, c = idx >> 6;
    tile[d * 65 + c] = f2bf(src[(long)(c0 + c) * 64 + d]);
  }
  __syncthreads();
  const long nb = (long)(mat * 1024 + h * 64);
#pragma unroll
  for (int i = 0; i < 16; ++i) {
    const int idx = i * 256 + t;
    const int d = idx >> 6, c = idx & 63;
    dst[(nb + d) * 1024 + c0 + c] = tile[d * 65 + c];
  }
}

// ---------------------------------------------------------------------------
// V transpose: qkv[B*T,3072] V-part -> Vt[bh][64 d][2048 t] bf16,
// with kv-columns PERMUTED within each 64-t group:
//   col c = g*8+j  holds kv = 2g + 16*(j&3) + (j>>2)
// (must match the attention P-tile column layout; MFMA contraction invariant)
// ---------------------------------------------------------------------------
__global__ __launch_bounds__(256) void vtrans(
    const u16* __restrict__ qkv, u16* __restrict__ vtg)
{
  __shared__ __attribute__((aligned(16))) u32 tile[64 * 33];
  const int t = threadIdx.x;
  const int tt = blockIdx.x, bh = blockIdx.y;
  const long bt0 = (long)(bh >> 4) * 2048;
  const int h = bh & 15;
  const int t0 = tt * 64;
  const int r2 = t >> 3, c8 = t & 7;
  const u16* src = qkv + (bt0 + t0 + 2 * r2) * 3072 + 2048 + h * 64 + c8 * 8;
  const s16x8 a = *(const s16x8*)src;
  const s16x8 b = *(const s16x8*)(src + 3072);
#pragma unroll
  for (int j = 0; j < 8; ++j)
    tile[(c8 * 8 + j) * 33 + r2] = (u32)(u16)a[j] | ((u32)(u16)b[j] << 16);
  __syncthreads();
  // stored col order per 16B group g: [2g,2g+16,2g+32,2g+48, 2g+1,2g+17,2g+33,2g+49]
#pragma unroll
  for (int it = 0; it < 2; ++it) {
    const int idx = it * 256 + t;
    const int d = idx >> 3, g = idx & 7;
    u32 p0 = tile[d * 33 + g];
    u32 p1 = tile[d * 33 + g + 8];
    u32 p2 = tile[d * 33 + g + 16];
    u32 p3 = tile[d * 33 + g + 24];
    u32x4 w;
    w[0] = (p0 & 0xffffu) | (p1 << 16);
    w[1] = (p2 & 0xffffu) | (p3 << 16);
    w[2] = (p0 >> 16) | (p1 & 0xffff0000u);
    w[3] = (p2 >> 16) | (p3 & 0xffff0000u);
    *(u32x4*)(vtg + (long)bh * 131072 + (long)d * 2048 + t0 + g * 8) = w;
  }
}

// ---------------------------------------------------------------------------
// LayerNorm: one wave per 1024-col row, fp32 in -> bf16 out
// ---------------------------------------------------------------------------
__global__ __launch_bounds__(256) void ln_kernel(
    const float* __restrict__ x, const float* __restrict__ g,
    const float* __restrict__ be, u16* __restrict__ out)
{
  const int t = threadIdx.x, wv = t >> 6, l = t & 63;
  const long row = (long)blockIdx.x * 4 + wv;
  const float* xr = x + row * 1024;
  f32x4 v[4];
#pragma unroll
  for (int i = 0; i < 4; ++i) v[i] = *(const f32x4*)(xr + i * 256 + l * 4);
  float s = 0.f, sq = 0.f;
#pragma unroll
  for (int i = 0; i < 4; ++i)
#pragma unroll
    for (int j = 0; j < 4; ++j) { s += v[i][j]; sq += v[i][j] * v[i][j]; }
#pragma unroll
  for (int mask = 1; mask < 64; mask <<= 1) {
    s  += __shfl_xor(s, mask);
    sq += __shfl_xor(sq, mask);
  }
  const float mean = s * (1.f / 1024.f);
  const float var  = sq * (1.f / 1024.f) - mean * mean;
  const float rs = rsqrtf(var + 1e-5f);
#pragma unroll
  for (int i = 0; i < 4; ++i) {
    f32x4 gv = *(const f32x4*)(g  + i * 256 + l * 4);
    f32x4 bv = *(const f32x4*)(be + i * 256 + l * 4);
    u16x4 o;
#pragma unroll
    for (int j = 0; j < 4; ++j) o[j] = f2bf((v[i][j] - mean) * rs * gv[j] + bv[j]);
    *(u16x4*)(out + row * 1024 + i * 256 + l * 4) = o;
  }
}

// ---------------------------------------------------------------------------
// GEMM v2: C[M,N] = A[M,K] * Bt[N,K]^T, 128x128 tile, BK=64,
// XOR-swizzled LDS, double-buffered 2-phase: one barrier per K-tile.
// ---------------------------------------------------------------------------
template <typename OutT, bool RELU, bool BIAS, bool RESID>
__global__ __launch_bounds__(256) void gemm_bt(
    const u16* __restrict__ A, const u16* __restrict__ Bt,
    OutT* __restrict__ Cout, const float* __restrict__ bias,
    const float* __restrict__ resid, int M, int N, int K)
{
  __shared__ __attribute__((aligned(16))) u16 As[2][8192];  // [128 m][64 k] swz
  __shared__ __attribute__((aligned(16))) u16 Bs[2][8192];  // [128 n][64 k] swz
  const int t  = threadIdx.x;
  const int l  = t & 63;
  const int wv = t >> 6;
  const int lr = l & 15, lg = l >> 4;
  const int wr = wv >> 1, wc = wv & 1;
  const long m0 = (long)blockIdx.x * 128, n0 = (long)blockIdx.y * 128;

  f32x4 acc[4][4] = {};

  const int srow8 = t >> 3;
  const int swc = ((t & 7) ^ (srow8 & 7)) << 3;
  const u16* Ap = A  + (m0 + srow8) * K + swc;
  const u16* Bp = Bt + (n0 + srow8) * K + swc;

#define GSTAGE(buf, kof)                                                      \
  {                                                                           \
    _Pragma("unroll")                                                         \
    for (int i = 0; i < 4; ++i) {                                             \
      g2l16(Ap + (long)i * 32 * K + (kof), (char*)As[buf] + (i * 256 + t) * 16); \
      g2l16(Bp + (long)i * 32 * K + (kof), (char*)Bs[buf] + (i * 256 + t) * 16); \
    }                                                                         \
  }

#define GCOMPUTE(buf)                                                         \
  {                                                                           \
    const char* Ab = (const char*)As[buf];                                    \
    const char* Bb = (const char*)Bs[buf];                                    \
    _Pragma("unroll")                                                         \
    for (int kk = 0; kk < 2; ++kk) {                                          \
      s16x8 af[4], bfr[4];                                                    \
      _Pragma("unroll")                                                       \
      for (int m = 0; m < 4; ++m) {                                           \
        const int row = wr * 64 + m * 16 + lr;                                \
        af[m] = *(const s16x8*)(Ab + row * 128 +                              \
                                ((((kk * 4 + lg) << 4) ^ ((row & 7) << 4)))); \
      }                                                                       \
      _Pragma("unroll")                                                       \
      for (int n = 0; n < 4; ++n) {                                           \
        const int row = wc * 64 + n * 16 + lr;                                \
        bfr[n] = *(const s16x8*)(Bb + row * 128 +                             \
                                 ((((kk * 4 + lg) << 4) ^ ((row & 7) << 4))));\
      }                                                                       \
      _Pragma("unroll")                                                       \
      for (int m = 0; m < 4; ++m)                                             \
        _Pragma("unroll")                                                     \
        for (int n = 0; n < 4; ++n)                                           \
          acc[m][n] = __builtin_amdgcn_mfma_f32_16x16x32_bf16(af[m], bfr[n],  \
                                                              acc[m][n], 0, 0, 0); \
    }                                                                         \
  }

  const int nt = K >> 6;
  GSTAGE(0, 0);
  __syncthreads();
  int cur = 0;
  for (int tt = 0; tt < nt - 1; ++tt) {
    GSTAGE(cur ^ 1, (tt + 1) * 64);
    GCOMPUTE(cur);
    __syncthreads();
    cur ^= 1;
  }
  GCOMPUTE(cur);
#undef GSTAGE
#undef GCOMPUTE

  float bv[4];
#pragma unroll
  for (int n = 0; n < 4; ++n)
    bv[n] = BIAS ? bias[n0 + wc * 64 + n * 16 + lr] : 0.f;

#pragma unroll
  for (int m = 0; m < 4; ++m) {
#pragma unroll
    for (int i = 0; i < 4; ++i) {
      const long row = m0 + wr * 64 + m * 16 + lg * 4 + i;
#pragma unroll
      for (int n = 0; n < 4; ++n) {
        const long col = n0 + wc * 64 + n * 16 + lr;
        float v = acc[m][n][i] + bv[n];
        if (RESID) v += resid[row * N + col];
        if (RELU)  v = fmaxf(v, 0.f);
        if constexpr (sizeof(OutT) == 2) Cout[row * N + col] = f2bf(v);
        else                             Cout[row * N + col] = v;
      }
    }
  }
}

// ---------------------------------------------------------------------------
// Flash attention v4, causal, 16 heads, HD=64.
// XCD-grouped 1D grid (1024 blocks): xcd = lid&7 owns bh in [xcd*8, xcd*8+8)
// so each bh's 16 q-tile blocks share one XCD L2 (K/V becomes L2-resident).
// Double-buffered K/V staging: one barrier per chunk, load hidden under
// previous chunk's compute. Block does q-tile pair {qt, 31-qt} (33 chunks).
// ---------------------------------------------------------------------------
__global__ __launch_bounds__(256) void attn_kernel(
    const u16* __restrict__ qkv, const u16* __restrict__ vtg,
    u16* __restrict__ out)
{
  __shared__ __attribute__((aligned(16))) u16 Kl[2][4096];  // [64 kv][64 d] swz, dbuf
  __shared__ __attribute__((aligned(16))) u16 Vl[2][4096];  // [64 d][64 kvperm] swz, dbuf
  __shared__ __attribute__((aligned(16))) u16 Pl[4][1024];  // per-wave [16 q][64 kvperm] swz

  const float c2 = 0.18033688011112042f;  // 0.125 * log2(e)

  const int t  = threadIdx.x;
  const int wv = t >> 6, l = t & 63;
  const int lr = l & 15, lg = l >> 4;
  const int lid = (int)blockIdx.x;
  const int xcd = lid & 7, ii = lid >> 3;
  const int bh = xcd * 8 + (ii >> 4);     // all 16 blocks of bh on one XCD
  const int qt = ii & 15;
  const long bt0 = (long)(bh >> 4) * 2048;
  const int h = bh & 15;

  const int r0 = t >> 3, c8 = t & 7;
  const int swc = (c8 ^ (r0 & 7)) << 3;   // pre-swizzled source col
  const u16* ksrc = qkv + (bt0 + r0) * 3072 + 1024 + h * 64 + swc;
  const u16* vsrc = vtg + (long)bh * 131072 + (long)r0 * 2048 + swc;
  char* pw = (char*)Pl + wv * 2048;

#define ASTAGE(buf, s0)                                                \
  {                                                                    \
    g2l16(ksrc + (long)(s0) * 3072,        (char*)Kl[buf] + t * 16);   \
    g2l16(ksrc + (long)((s0) + 32) * 3072, (char*)Kl[buf] + 4096 + t * 16); \
    g2l16(vsrc + (s0),                     (char*)Vl[buf] + t * 16);   \
    g2l16(vsrc + (s0) + 65536,             (char*)Vl[buf] + 4096 + t * 16); \
  }

#pragma unroll
  for (int half = 0; half < 2; ++half) {
    const int qte = half ? (31 - qt) : qt;
    const int qrow0 = qte * 64 + wv * 16;

    s16x8 aq[2];
#pragma unroll
    for (int dc = 0; dc < 2; ++dc)
      aq[dc] = *(const s16x8*)(qkv + (bt0 + qrow0 + lr) * 3072 + h * 64 + dc * 32 + lg * 8);

    f32x4 O[4] = {};
    float mi[4], li[4];
#pragma unroll
    for (int i = 0; i < 4; ++i) { mi[i] = -__builtin_inff(); li[i] = 0.f; }

    __syncthreads();            // all waves done with LDS from previous half
    ASTAGE(0, 0);
    int cur = 0;

    for (int scn = 0; scn <= qte; ++scn) {
      __syncthreads();          // stage(cur) landed; buf cur^1 free
      if (scn < qte) ASTAGE(cur ^ 1, (scn + 1) * 64);

      const int s0 = scn * 64;
      const char* Kb = (const char*)Kl[cur];
      const char* Vb = (const char*)Vl[cur];

      // K fragments (B-operand): [kv-tile][d-half]
      s16x8 kf[4][2];
#pragma unroll
      for (int n = 0; n < 4; ++n) {
        const int row = n * 16 + lr;
        const int sw = (row & 7) << 4;
#pragma unroll
        for (int dh = 0; dh < 2; ++dh)
          kf[n][dh] = *(const s16x8*)(Kb + row * 128 + (((dh * 4 + lg) << 4) ^ sw));
      }

      f32x4 S[4];
#pragma unroll
      for (int n = 0; n < 4; ++n) {
        f32x4 z = {};
        z = __builtin_amdgcn_mfma_f32_16x16x32_bf16(aq[0], kf[n][0], z, 0, 0, 0);
        S[n] = __builtin_amdgcn_mfma_f32_16x16x32_bf16(aq[1], kf[n][1], z, 0, 0, 0);
      }

      float mt[4];
      if (scn == qte) {  // diagonal chunk: causal mask
#pragma unroll
        for (int i = 0; i < 4; ++i) {
          const int qg = qrow0 + lg * 4 + i;
#pragma unroll
          for (int n = 0; n < 4; ++n)
            S[n][i] = (s0 + n * 16 + lr <= qg) ? S[n][i] : -__builtin_inff();
          mt[i] = fmaxf(fmaxf(S[0][i], S[1][i]), fmaxf(S[2][i], S[3][i]));
        }
      } else {
#pragma unroll
        for (int i = 0; i < 4; ++i)
          mt[i] = fmaxf(fmaxf(S[0][i], S[1][i]), fmaxf(S[2][i], S[3][i]));
      }
#pragma unroll
      for (int msk = 1; msk < 16; msk <<= 1)
#pragma unroll
        for (int i = 0; i < 4; ++i)
          mt[i] = fmaxf(mt[i], __shfl_xor(mt[i], msk));

      // defer-max: skip rescale pass when no lane's max grew (exact)
      const int grow = (mt[0] > mi[0]) | (mt[1] > mi[1]) |
                       (mt[2] > mi[2]) | (mt[3] > mi[3]);
      if (__any(grow)) {
#pragma unroll
        for (int i = 0; i < 4; ++i) {
          const float mn = fmaxf(mi[i], mt[i]);
          const float so = fexp2((mi[i] - mn) * c2);
          mi[i] = mn;
          li[i] *= so;
#pragma unroll
          for (int n = 0; n < 4; ++n) O[n][i] *= so;
        }
      }

      // P = exp2(c2*(S - mi)) -> bf16 pairs -> ds_write_b64
#pragma unroll
      for (int i = 0; i < 4; ++i) {
        const float nmc = -mi[i] * c2;
        float p[4];
#pragma unroll
        for (int n = 0; n < 4; ++n) p[n] = fexp2(fmaf(S[n][i], c2, nmc));
        li[i] += (p[0] + p[1]) + (p[2] + p[3]);
        const int q_l = lg * 4 + i;
        u32x2 pk;
        pk[0] = (u32)f2bf(p[0]) | ((u32)f2bf(p[1]) << 16);
        pk[1] = (u32)f2bf(p[2]) | ((u32)f2bf(p[3]) << 16);
        *(u32x2*)(pw + q_l * 128 + ((((lr >> 1) << 4) ^ ((q_l & 7) << 4)) + ((lr & 1) << 3))) = pk;
      }

      // V fragments (B-operand, kv-permuted cols): [d-tile][kv-half]
      s16x8 vf[4][2];
#pragma unroll
      for (int dn = 0; dn < 4; ++dn) {
        const int row = dn * 16 + lr;
        const int sw = (row & 7) << 4;
#pragma unroll
        for (int kk = 0; kk < 2; ++kk)
          vf[dn][kk] = *(const s16x8*)(Vb + row * 128 + (((kk * 4 + lg) << 4) ^ sw));
      }
      // P fragments (A-operand): row = lr
      s16x8 pa[2];
#pragma unroll
      for (int kk = 0; kk < 2; ++kk)
        pa[kk] = *(const s16x8*)(pw + lr * 128 + (((kk * 4 + lg) << 4) ^ ((lr & 7) << 4)));
#pragma unroll
      for (int dn = 0; dn < 4; ++dn) {
        O[dn] = __builtin_amdgcn_mfma_f32_16x16x32_bf16(pa[0], vf[dn][0], O[dn], 0, 0, 0);
        O[dn] = __builtin_amdgcn_mfma_f32_16x16x32_bf16(pa[1], vf[dn][1], O[dn], 0, 0, 0);
      }
      cur ^= 1;
    }

#pragma unroll
    for (int msk = 1; msk < 16; msk <<= 1)
#pragma unroll
      for (int i = 0; i < 4; ++i)
        li[i] += __shfl_xor(li[i], msk);

#pragma unroll
    for (int i = 0; i < 4; ++i) {
      const float rl = 1.f / li[i];
      const long ob = (bt0 + qrow0 + lg * 4 + i) * 1024 + h * 64 + lr;
#pragma unroll
      for (int n = 0; n < 4; ++n)
        out[ob + n * 16] = f2bf(O[n][i] * rl);
    }
  }
#undef ASTAGE
}

// ---------------------------------------------------------------------------
extern "C" void kernel_launch(void* const* d_in, const int* in_sizes, int n_in,
                              void* d_out, int out_size, void* d_ws, size_t ws_size,
                              hipStream_t stream)
{
  const float* x   = (const float*)d_in[0];
  const float* Wq  = (const float*)d_in[1];
  const float* Wk  = (const float*)d_in[2];
  const float* Wv  = (const float*)d_in[3];
  const float* Wo  = (const float*)d_in[4];
  const float* bo  = (const float*)d_in[5];
  const float* W1  = (const float*)d_in[6];
  const float* b1  = (const float*)d_in[7];
  const float* W2  = (const float*)d_in[8];
  const float* b2  = (const float*)d_in[9];
  const float* g1  = (const float*)d_in[10];
  const float* be1 = (const float*)d_in[11];
  const float* g2  = (const float*)d_in[12];
  const float* be2 = (const float*)d_in[13];
  float* outp = (float*)d_out;

  char* ws = (char*)d_ws;
  u16*   qkvT = (u16*)ws;                       //  6,291,456  [3072,1024] bf16
  u16*   woT  = (u16*)(ws + 6291456);           //  2,097,152
  u16*   w1T  = (u16*)(ws + 8388608);           //  8,388,608  [4096,1024]
  u16*   w2T  = (u16*)(ws + 16777216);          //  8,388,608  [1024,4096]
  float* x2   = (float*)(ws + 25165824);        // 33,554,432  [8192,1024] f32
  u16*   attno= (u16*)(ws + 58720256);          // 16,777,216
  u16*   h2   = (u16*)(ws + 75497472);          // 16,777,216
  u16*   hbf  = (u16*)(ws + 92274688);          // 16,777,216 (LN1 out; dead after QKV GEMM)
  u16*   vtg  = (u16*)(ws + 92274688);          // 16,777,216 Vt (alias hbf; written after)
  u16*   qkvb = (u16*)(ws + 109051904);         // 50,331,648  [8192,3072]
  u16*   ffn1 = (u16*)(ws + 92274688);          // reuse vtg+qkvb region after attention
  (void)in_sizes; (void)n_in; (void)out_size; (void)ws_size;

  // weight conversion
  trans_qkvw<<<dim3(16, 48), 256, 0, stream>>>(Wq, Wk, Wv, qkvT);
  trans_w<<<dim3(16, 16), 256, 0, stream>>>(Wo, woT, 1024, 1024);
  trans_w<<<dim3(64, 16), 256, 0, stream>>>(W1, w1T, 1024, 4096);
  trans_w<<<dim3(16, 64), 256, 0, stream>>>(W2, w2T, 4096, 1024);

  // LN1 -> hbf (bf16)
  ln_kernel<<<2048, 256, 0, stream>>>(x, g1, be1, hbf);
  // QKV projection
  gemm_bt<u16, false, false, false><<<dim3(64, 24), 256, 0, stream>>>(
      hbf, qkvT, qkvb, nullptr, nullptr, 8192, 3072, 1024);
  // V transpose (kv-permuted) to [bh][64][2048]
  vtrans<<<dim3(32, 64), 256, 0, stream>>>(qkvb, vtg);
  // causal flash attention (XCD-grouped 1D grid)
  attn_kernel<<<1024, 256, 0, stream>>>(qkvb, vtg, attno);
  // output projection + bias + residual -> x2 (f32)
  gemm_bt<float, false, true, true><<<dim3(64, 8), 256, 0, stream>>>(
      attno, woT, x2, bo, x, 8192, 1024, 1024);
  // LN2 -> h2 (bf16)
  ln_kernel<<<2048, 256, 0, stream>>>(x2, g2, be2, h2);
  // FFN1 + bias + relu -> bf16
  gemm_bt<u16, true, true, false><<<dim3(64, 32), 256, 0, stream>>>(
      h2, w1T, ffn1, b1, nullptr, 8192, 4096, 1024);
  // FFN2 + bias + residual -> d_out (f32)
  gemm_bt<float, false, true, true><<<dim3(64, 8), 256, 0, stream>>>(
      ffn1, w2T, outp, b2, x2, 8192, 1024, 4096);
}